// Round 1
// baseline (946.726 us; speedup 1.0000x reference)
//
#include <hip/hip_runtime.h>
#include <hip/hip_bf16.h>
#include <math.h>

// Problem dims (fixed)
constexpr int TDIM = 256;   // sequence length t
constexpr int CDIM = 256;   // channels C
constexpr int NH   = 4;     // heads
constexpr int DHS  = 64;    // head size
constexpr int FHID = 1024;  // ffn hidden
constexpr int NV   = 8000;  // vocab
constexpr int NB   = 2;     // batch

__device__ __forceinline__ float gelu_f(float x) {
    return 0.5f * x * (1.0f + erff(x * 0.70710678118654752440f));
}

// x[b,t,:] = tok_emb[idx[b,t]]
__global__ void k_embed(const int* __restrict__ idx, const float* __restrict__ tok_emb,
                        float* __restrict__ x) {
    int bt = blockIdx.x;           // 0..511
    int c  = threadIdx.x;          // 256
    int tok = idx[bt];
    x[bt * CDIM + c] = tok_emb[(size_t)tok * CDIM + c];
}

// peh[d,:512] = gelu(pos_table[d] @ pos_w1)   (d = i-j distance, 256 rows only!)
__global__ void k_pe1(const float* __restrict__ pos_table, const float* __restrict__ pos_w1,
                      float* __restrict__ peh) {
    int d = blockIdx.x;
    int t = threadIdx.x;           // 512
    __shared__ float xs[CDIM];
    if (t < CDIM) xs[t] = pos_table[d * CDIM + t];
    __syncthreads();
    float acc = 0.f;
    for (int c = 0; c < CDIM; ++c) acc += xs[c] * pos_w1[(size_t)c * 512 + t];
    peh[d * 512 + t] = gelu_f(acc);
}

// ped[d,:512] = LN(peh[d] @ pos_w2 + pos_b2)
__global__ void k_pe2(const float* __restrict__ peh, const float* __restrict__ pos_w2,
                      const float* __restrict__ pos_b2, const float* __restrict__ g,
                      const float* __restrict__ bb, float* __restrict__ ped) {
    int d = blockIdx.x;
    int t = threadIdx.x;           // 512
    __shared__ float hs[512];
    __shared__ float red[512];
    hs[t] = peh[d * 512 + t];
    __syncthreads();
    float acc = pos_b2[t];
    for (int z = 0; z < 512; ++z) acc += hs[z] * pos_w2[(size_t)z * 512 + t];
    red[t] = acc; __syncthreads();
    for (int s = 256; s > 0; s >>= 1) { if (t < s) red[t] += red[t + s]; __syncthreads(); }
    float mean = red[0] * (1.f / 512.f); __syncthreads();
    float dv = acc - mean;
    red[t] = dv * dv; __syncthreads();
    for (int s = 256; s > 0; s >>= 1) { if (t < s) red[t] += red[t + s]; __syncthreads(); }
    float r = rsqrtf(red[0] * (1.f / 512.f) + 1e-5f);
    ped[d * 512 + t] = dv * r * g[t] + bb[t];
}

// P_T[b,h,c,j] = x[b,j] @ W1_top[h,:,c];  Q[b,i,h,c] = x[b,i] @ W1_bot[h,:,c]
// 4 rows per block for weight reuse. 512 threads.
__global__ void k_pq(const float* __restrict__ x, const float* __restrict__ att_w1,
                     int l, float* __restrict__ PT, float* __restrict__ Qb) {
    int bi0 = blockIdx.x * 4;
    int b = bi0 >> 8;
    int j0 = bi0 & 255;
    int t = threadIdx.x;           // 512
    __shared__ float xs[4][CDIM];
    for (int q = t; q < 4 * CDIM; q += 512) xs[q >> 8][q & 255] = x[bi0 * CDIM + q];
    __syncthreads();
    for (int u = t; u < 2048; u += 512) {
        int isQ = u >> 10;
        int hc = u & 1023;
        int h = hc >> 8, c = hc & 255;
        const float* w = att_w1 + ((size_t)((l * NH + h) * 512 + isQ * 256)) * CDIM + c;
        float a0 = 0, a1 = 0, a2 = 0, a3 = 0;
        for (int z = 0; z < CDIM; ++z) {
            float wv = w[(size_t)z * CDIM];
            a0 += xs[0][z] * wv; a1 += xs[1][z] * wv;
            a2 += xs[2][z] * wv; a3 += xs[3][z] * wv;
        }
        if (isQ) {
            Qb[((bi0 + 0) * NH + h) * CDIM + c] = a0;
            Qb[((bi0 + 1) * NH + h) * CDIM + c] = a1;
            Qb[((bi0 + 2) * NH + h) * CDIM + c] = a2;
            Qb[((bi0 + 3) * NH + h) * CDIM + c] = a3;
        } else {
            float* p = PT + ((size_t)(b * NH + h) * CDIM + c) * TDIM + j0;
            p[0] = a0; p[1] = a1; p[2] = a2; p[3] = a3;
        }
    }
}

// R_T[h,c,d] = ped[d] @ W1[h,:,c]  (full 512 rows). 4 d's per block, 512 threads.
__global__ void k_r(const float* __restrict__ ped, const float* __restrict__ att_w1,
                    int l, float* __restrict__ RT) {
    int d0 = blockIdx.x * 4;
    int t = threadIdx.x;           // 512
    __shared__ float ps[4][512];
    for (int q = t; q < 2048; q += 512) ps[q >> 9][q & 511] = ped[d0 * 512 + q];
    __syncthreads();
    for (int u = t; u < 1024; u += 512) {
        int h = u >> 8, c = u & 255;
        const float* w = att_w1 + ((size_t)(l * NH + h) * 512) * CDIM + c;
        float a0 = 0, a1 = 0, a2 = 0, a3 = 0;
        for (int z = 0; z < 512; ++z) {
            float wv = w[(size_t)z * CDIM];
            a0 += ps[0][z] * wv; a1 += ps[1][z] * wv;
            a2 += ps[2][z] * wv; a3 += ps[3][z] * wv;
        }
        float* rp = RT + ((size_t)h * CDIM + c) * TDIM + d0;
        rp[0] = a0; rp[1] = a1; rp[2] = a2; rp[3] = a3;
    }
}

// v[b,h,j,d] = x[b,j] @ val_w[l,h,:,d]. 4 rows/block, 256 threads = (h,d).
__global__ void k_v(const float* __restrict__ x, const float* __restrict__ val_w,
                    int l, float* __restrict__ vbuf) {
    int bi0 = blockIdx.x * 4;
    int b = bi0 >> 8;
    int j0 = bi0 & 255;
    int t = threadIdx.x;           // 256
    __shared__ float xs[4][CDIM];
    for (int q = t; q < 4 * CDIM; q += 256) xs[q >> 8][q & 255] = x[bi0 * CDIM + q];
    __syncthreads();
    int h = t >> 6, d = t & 63;
    const float* w = val_w + ((size_t)(l * NH + h) * CDIM) * DHS + d;
    float a0 = 0, a1 = 0, a2 = 0, a3 = 0;
    for (int c = 0; c < CDIM; ++c) {
        float wv = w[(size_t)c * DHS];
        a0 += xs[0][c] * wv; a1 += xs[1][c] * wv;
        a2 += xs[2][c] * wv; a3 += xs[3][c] * wv;
    }
    float* vp = vbuf + ((size_t)(b * NH + h) * TDIM + j0) * DHS + d;
    vp[0 * DHS] = a0; vp[1 * DHS] = a1; vp[2 * DHS] = a2; vp[3 * DHS] = a3;
}

// wei[b,h,i,j] = softmax_j( (sum_c gelu(P[b,j,h,c]+Q[b,i,h,c]+R[i-j,h,c])*w2[h,c] + b2)*scale )
// block per (b,h,i); thread = j; only j<=i computed (causal).
__global__ void k_wei(const float* __restrict__ PT, const float* __restrict__ Qb,
                      const float* __restrict__ RT, const float* __restrict__ att_w2,
                      const float* __restrict__ att_b2, int l, float* __restrict__ wei) {
    int bid = blockIdx.x;
    int i = bid & 255;
    int h = (bid >> 8) & (NH - 1);
    int b = bid >> 10;
    int t = threadIdx.x;           // j, 256
    __shared__ float qs[CDIM];
    __shared__ float w2s[CDIM];
    __shared__ float red[TDIM];
    qs[t]  = Qb[((b * TDIM + i) * NH + h) * CDIM + t];
    w2s[t] = att_w2[(l * NH + h) * CDIM + t];
    __syncthreads();
    float acc = 0.f;
    if (t <= i) {
        const float* pp = PT + ((size_t)(b * NH + h) * CDIM) * TDIM + t;
        const float* rr = RT + ((size_t)h * CDIM) * TDIM + (i - t);
        for (int c = 0; c < CDIM; ++c) {
            float z = pp[(size_t)c * TDIM] + qs[c] + rr[(size_t)c * TDIM];
            acc += gelu_f(z) * w2s[c];
        }
    }
    float logit = (acc + att_b2[l * NH + h]) * 0.0625f;  // scale = C^-0.5 = 1/16
    red[t] = (t <= i) ? logit : -1e30f;
    __syncthreads();
    for (int s = 128; s > 0; s >>= 1) { if (t < s) red[t] = fmaxf(red[t], red[t + s]); __syncthreads(); }
    float mx = red[0]; __syncthreads();
    float e = (t <= i) ? __expf(logit - mx) : 0.f;
    red[t] = e; __syncthreads();
    for (int s = 128; s > 0; s >>= 1) { if (t < s) red[t] += red[t + s]; __syncthreads(); }
    float inv = 1.f / red[0];
    if (t <= i) wei[((size_t)(b * NH + h) * TDIM + i) * TDIM + t] = e * inv;
}

// attn[b,i,h*64+d] = sum_{j<=i} wei[b,h,i,j] * v[b,h,j,d]. block per (b,h,i), 64 threads.
__global__ void k_av(const float* __restrict__ wei, const float* __restrict__ vbuf,
                     float* __restrict__ attn) {
    int bid = blockIdx.x;
    int i = bid & 255;
    int h = (bid >> 8) & (NH - 1);
    int b = bid >> 10;
    int d = threadIdx.x;           // 64
    const float* wrow = wei + ((size_t)(b * NH + h) * TDIM + i) * TDIM;
    const float* vp = vbuf + ((size_t)(b * NH + h) * TDIM) * DHS + d;
    float acc = 0.f;
    for (int j = 0; j <= i; ++j) acc += wrow[j] * vp[(size_t)j * DHS];
    attn[(b * TDIM + i) * CDIM + h * DHS + d] = acc;
}

// x += attn @ proj_w + proj_b. 4 rows/block, 256 threads.
__global__ void k_proj(const float* __restrict__ attn, const float* __restrict__ proj_w,
                       const float* __restrict__ proj_b, int l, float* __restrict__ x) {
    int bi0 = blockIdx.x * 4;
    int t = threadIdx.x;           // 256
    __shared__ float as[4][CDIM];
    for (int q = t; q < 4 * CDIM; q += 256) as[q >> 8][q & 255] = attn[bi0 * CDIM + q];
    __syncthreads();
    const float* w = proj_w + (size_t)l * CDIM * CDIM + t;
    float bb = proj_b[l * CDIM + t];
    float a0 = bb, a1 = bb, a2 = bb, a3 = bb;
    for (int z = 0; z < CDIM; ++z) {
        float wv = w[(size_t)z * CDIM];
        a0 += as[0][z] * wv; a1 += as[1][z] * wv;
        a2 += as[2][z] * wv; a3 += as[3][z] * wv;
    }
    x[(bi0 + 0) * CDIM + t] += a0; x[(bi0 + 1) * CDIM + t] += a1;
    x[(bi0 + 2) * CDIM + t] += a2; x[(bi0 + 3) * CDIM + t] += a3;
}

// out[row] = LN(in[row]) * g + b, C=256. block per row.
__global__ void k_ln256(const float* __restrict__ x, const float* __restrict__ g,
                        const float* __restrict__ bb, float* __restrict__ out) {
    int bi = blockIdx.x;
    int t = threadIdx.x;           // 256
    __shared__ float red[CDIM];
    float val = x[bi * CDIM + t];
    red[t] = val; __syncthreads();
    for (int s = 128; s > 0; s >>= 1) { if (t < s) red[t] += red[t + s]; __syncthreads(); }
    float mean = red[0] * (1.f / 256.f); __syncthreads();
    float dv = val - mean;
    red[t] = dv * dv; __syncthreads();
    for (int s = 128; s > 0; s >>= 1) { if (t < s) red[t] += red[t + s]; __syncthreads(); }
    float r = rsqrtf(red[0] * (1.f / 256.f) + 1e-5f);
    out[bi * CDIM + t] = dv * r * g[t] + bb[t];
}

// f = gelu(h @ ff_w1). 4 rows/block, 512 threads.
__global__ void k_ff1(const float* __restrict__ h, const float* __restrict__ ff_w1,
                      int l, float* __restrict__ f) {
    int bi0 = blockIdx.x * 4;
    int t = threadIdx.x;           // 512
    __shared__ float hs[4][CDIM];
    for (int q = t; q < 4 * CDIM; q += 512) hs[q >> 8][q & 255] = h[bi0 * CDIM + q];
    __syncthreads();
    for (int u = t; u < FHID; u += 512) {
        const float* w = ff_w1 + (size_t)l * CDIM * FHID + u;
        float a0 = 0, a1 = 0, a2 = 0, a3 = 0;
        for (int c = 0; c < CDIM; ++c) {
            float wv = w[(size_t)c * FHID];
            a0 += hs[0][c] * wv; a1 += hs[1][c] * wv;
            a2 += hs[2][c] * wv; a3 += hs[3][c] * wv;
        }
        f[(bi0 + 0) * FHID + u] = gelu_f(a0);
        f[(bi0 + 1) * FHID + u] = gelu_f(a1);
        f[(bi0 + 2) * FHID + u] = gelu_f(a2);
        f[(bi0 + 3) * FHID + u] = gelu_f(a3);
    }
}

// x += f @ ff_w2 + ff_b2. 4 rows/block, 256 threads.
__global__ void k_ff2(const float* __restrict__ f, const float* __restrict__ ff_w2,
                      const float* __restrict__ ff_b2, int l, float* __restrict__ x) {
    int bi0 = blockIdx.x * 4;
    int t = threadIdx.x;           // 256
    __shared__ float fs[4][FHID];
    for (int q = t; q < 4 * FHID; q += 256) fs[q >> 10][q & 1023] = f[bi0 * FHID + q];
    __syncthreads();
    const float* w = ff_w2 + (size_t)l * FHID * CDIM + t;
    float bb = ff_b2[l * CDIM + t];
    float a0 = bb, a1 = bb, a2 = bb, a3 = bb;
    for (int u = 0; u < FHID; ++u) {
        float wv = w[(size_t)u * CDIM];
        a0 += fs[0][u] * wv; a1 += fs[1][u] * wv;
        a2 += fs[2][u] * wv; a3 += fs[3][u] * wv;
    }
    x[(bi0 + 0) * CDIM + t] += a0; x[(bi0 + 1) * CDIM + t] += a1;
    x[(bi0 + 2) * CDIM + t] += a2; x[(bi0 + 3) * CDIM + t] += a3;
}

// logits = xf @ head_w + head_b. 8 rows per block, grid.y splits vocab.
__global__ void k_head(const float* __restrict__ xf, const float* __restrict__ head_w,
                       const float* __restrict__ head_b, float* __restrict__ out) {
    int r0 = blockIdx.x * 8;
    int t = threadIdx.x;           // 256
    __shared__ float xs[8][CDIM];
    for (int q = t; q < 8 * CDIM; q += 256) xs[q >> 8][q & 255] = xf[r0 * CDIM + q];
    __syncthreads();
    for (int vv = blockIdx.y * 256 + t; vv < NV; vv += 1024) {
        float hb = head_b[vv];
        float acc[8];
        #pragma unroll
        for (int r = 0; r < 8; ++r) acc[r] = hb;
        const float* w = head_w + vv;
        for (int c = 0; c < CDIM; ++c) {
            float wv = w[(size_t)c * NV];
            #pragma unroll
            for (int r = 0; r < 8; ++r) acc[r] += xs[r][c] * wv;
        }
        #pragma unroll
        for (int r = 0; r < 8; ++r) out[(size_t)(r0 + r) * NV + vv] = acc[r];
    }
}

extern "C" void kernel_launch(void* const* d_in, const int* in_sizes, int n_in,
                              void* d_out, int out_size, void* d_ws, size_t ws_size,
                              hipStream_t stream) {
    const int*   idx       = (const int*)  d_in[0];
    const float* tok_emb   = (const float*)d_in[1];
    const float* pos_table = (const float*)d_in[2];
    const float* pos_w1    = (const float*)d_in[3];
    const float* pos_w2    = (const float*)d_in[4];
    const float* pos_b2    = (const float*)d_in[5];
    const float* pos_ln_g  = (const float*)d_in[6];
    const float* pos_ln_b  = (const float*)d_in[7];
    const float* att_w1    = (const float*)d_in[8];
    const float* att_w2    = (const float*)d_in[9];
    const float* att_b2    = (const float*)d_in[10];
    const float* val_w     = (const float*)d_in[11];
    const float* proj_w    = (const float*)d_in[12];
    const float* proj_b    = (const float*)d_in[13];
    const float* ln2_g     = (const float*)d_in[14];
    const float* ln2_b     = (const float*)d_in[15];
    const float* ff_w1     = (const float*)d_in[16];
    const float* ff_w2     = (const float*)d_in[17];
    const float* ff_b2     = (const float*)d_in[18];
    const float* lnf_g     = (const float*)d_in[19];
    const float* lnf_b     = (const float*)d_in[20];
    const float* head_w    = (const float*)d_in[21];
    const float* head_b    = (const float*)d_in[22];
    float* out = (float*)d_out;

    float* ws = (float*)d_ws;
    float* x    = ws;  ws += NB * TDIM * CDIM;        // 131072
    float* peh  = ws;  ws += TDIM * 2 * CDIM;         // 131072
    float* ped  = ws;  ws += TDIM * 2 * CDIM;         // 131072
    float* PT   = ws;  ws += NB * NH * CDIM * TDIM;   // 524288
    float* Qb   = ws;  ws += NB * TDIM * NH * CDIM;   // 524288
    float* RT   = ws;  ws += NH * CDIM * TDIM;        // 262144
    float* vbuf = ws;  ws += NB * NH * TDIM * DHS;    // 131072
    float* wei  = ws;  ws += NB * NH * TDIM * TDIM;   // 524288
    float* attn = ws;  ws += NB * TDIM * CDIM;        // 131072
    float* hbuf = ws;  ws += NB * TDIM * CDIM;        // 131072
    float* fbuf = ws;  ws += NB * TDIM * FHID;        // 524288
    float* xf   = ws;  ws += NB * TDIM * CDIM;        // 131072
    // total ~3.28M floats = 13.1 MB

    k_embed<<<NB * TDIM, CDIM, 0, stream>>>(idx, tok_emb, x);
    k_pe1<<<TDIM, 512, 0, stream>>>(pos_table, pos_w1, peh);
    k_pe2<<<TDIM, 512, 0, stream>>>(peh, pos_w2, pos_b2, pos_ln_g, pos_ln_b, ped);

    for (int l = 0; l < 2; ++l) {
        k_pq<<<NB * TDIM / 4, 512, 0, stream>>>(x, att_w1, l, PT, Qb);
        k_r<<<TDIM / 4, 512, 0, stream>>>(ped, att_w1, l, RT);
        k_v<<<NB * TDIM / 4, 256, 0, stream>>>(x, val_w, l, vbuf);
        k_wei<<<NB * NH * TDIM, 256, 0, stream>>>(PT, Qb, RT, att_w2, att_b2, l, wei);
        k_av<<<NB * NH * TDIM, 64, 0, stream>>>(wei, vbuf, attn);
        k_proj<<<NB * TDIM / 4, 256, 0, stream>>>(attn, proj_w, proj_b, l, x);
        k_ln256<<<NB * TDIM, 256, 0, stream>>>(x, ln2_g + l * CDIM, ln2_b + l * CDIM, hbuf);
        k_ff1<<<NB * TDIM / 4, 512, 0, stream>>>(hbuf, ff_w1, l, fbuf);
        k_ff2<<<NB * TDIM / 4, 256, 0, stream>>>(fbuf, ff_w2, ff_b2, l, x);
    }

    k_ln256<<<NB * TDIM, 256, 0, stream>>>(x, lnf_g, lnf_b, xf);
    dim3 hg(NB * TDIM / 8, 4);
    k_head<<<hg, 256, 0, stream>>>(xf, head_w, head_b, out);
}

// Round 2
// 612.943 us; speedup vs baseline: 1.5446x; 1.5446x over previous
//
#include <hip/hip_runtime.h>
#include <hip/hip_bf16.h>
#include <math.h>

// Problem dims (fixed)
constexpr int TDIM = 256;   // sequence length t
constexpr int CDIM = 256;   // channels C
constexpr int NH   = 4;     // heads
constexpr int DHS  = 64;    // head size
constexpr int FHID = 1024;  // ffn hidden
constexpr int NV   = 8000;  // vocab
constexpr int NB   = 2;     // batch

typedef __attribute__((ext_vector_type(8))) short bf16x8;
typedef __attribute__((ext_vector_type(4))) float f32x4;
typedef __attribute__((ext_vector_type(4))) unsigned int uint4v;

__device__ __forceinline__ float gelu_f(float x) {
    return 0.5f * x * (1.0f + erff(x * 0.70710678118654752440f));
}

__device__ __forceinline__ unsigned short f2bf(float f) {
    unsigned int u = __float_as_uint(f);
    unsigned int r = (u + 0x7FFF + ((u >> 16) & 1)) >> 16;   // RNE
    return (unsigned short)r;
}

// x[b,t,:] = tok_emb[idx[b,t]]
__global__ void k_embed(const int* __restrict__ idx, const float* __restrict__ tok_emb,
                        float* __restrict__ x) {
    int bt = blockIdx.x;           // 0..511
    int c  = threadIdx.x;          // 256
    int tok = idx[bt];
    x[bt * CDIM + c] = tok_emb[(size_t)tok * CDIM + c];
}

// peh[d,:512] = gelu(pos_table[d] @ pos_w1)
__global__ void k_pe1(const float* __restrict__ pos_table, const float* __restrict__ pos_w1,
                      float* __restrict__ peh) {
    int d = blockIdx.x;
    int t = threadIdx.x;           // 512
    __shared__ float xs[CDIM];
    if (t < CDIM) xs[t] = pos_table[d * CDIM + t];
    __syncthreads();
    float acc = 0.f;
    for (int c = 0; c < CDIM; ++c) acc += xs[c] * pos_w1[(size_t)c * 512 + t];
    peh[d * 512 + t] = gelu_f(acc);
}

// ped[d,:512] = LN(peh[d] @ pos_w2 + pos_b2)
__global__ void k_pe2(const float* __restrict__ peh, const float* __restrict__ pos_w2,
                      const float* __restrict__ pos_b2, const float* __restrict__ g,
                      const float* __restrict__ bb, float* __restrict__ ped) {
    int d = blockIdx.x;
    int t = threadIdx.x;           // 512
    __shared__ float hs[512];
    __shared__ float red[512];
    hs[t] = peh[d * 512 + t];
    __syncthreads();
    float acc = pos_b2[t];
    for (int z = 0; z < 512; ++z) acc += hs[z] * pos_w2[(size_t)z * 512 + t];
    red[t] = acc; __syncthreads();
    for (int s = 256; s > 0; s >>= 1) { if (t < s) red[t] += red[t + s]; __syncthreads(); }
    float mean = red[0] * (1.f / 512.f); __syncthreads();
    float dv = acc - mean;
    red[t] = dv * dv; __syncthreads();
    for (int s = 256; s > 0; s >>= 1) { if (t < s) red[t] += red[t + s]; __syncthreads(); }
    float r = rsqrtf(red[0] * (1.f / 512.f) + 1e-5f);
    ped[d * 512 + t] = dv * r * g[t] + bb[t];
}

// P_T[b,h,c,j]; Q[b,i,h,c]. 4 rows/block, u-slice across grid.y (weight traffic unchanged).
__global__ void k_pq(const float* __restrict__ x, const float* __restrict__ att_w1,
                     int l, float* __restrict__ PT, float* __restrict__ Qb) {
    int bi0 = blockIdx.x * 4;
    int b = bi0 >> 8;
    int j0 = bi0 & 255;
    int t = threadIdx.x;           // 512
    int u = blockIdx.y * 512 + t;  // 0..2047
    __shared__ float xs[4][CDIM];
    for (int q = t; q < 4 * CDIM; q += 512) xs[q >> 8][q & 255] = x[bi0 * CDIM + q];
    __syncthreads();
    int isQ = u >> 10;
    int hc = u & 1023;
    int h = hc >> 8, c = hc & 255;
    const float* w = att_w1 + ((size_t)((l * NH + h) * 512 + isQ * 256)) * CDIM + c;
    float a0 = 0, a1 = 0, a2 = 0, a3 = 0;
    for (int z = 0; z < CDIM; ++z) {
        float wv = w[(size_t)z * CDIM];
        a0 += xs[0][z] * wv; a1 += xs[1][z] * wv;
        a2 += xs[2][z] * wv; a3 += xs[3][z] * wv;
    }
    if (isQ) {
        Qb[((bi0 + 0) * NH + h) * CDIM + c] = a0;
        Qb[((bi0 + 1) * NH + h) * CDIM + c] = a1;
        Qb[((bi0 + 2) * NH + h) * CDIM + c] = a2;
        Qb[((bi0 + 3) * NH + h) * CDIM + c] = a3;
    } else {
        float* p = PT + ((size_t)(b * NH + h) * CDIM + c) * TDIM + j0;
        p[0] = a0; p[1] = a1; p[2] = a2; p[3] = a3;
    }
}

// R_T[h,c,d] = ped[d] @ W1[h,:,c]. 4 d/block, u-slice across grid.y.
__global__ void k_r(const float* __restrict__ ped, const float* __restrict__ att_w1,
                    int l, float* __restrict__ RT) {
    int d0 = blockIdx.x * 4;
    int t = threadIdx.x;           // 512
    int u = blockIdx.y * 512 + t;  // 0..1023
    __shared__ float ps[4][512];
    for (int q = t; q < 2048; q += 512) ps[q >> 9][q & 511] = ped[d0 * 512 + q];
    __syncthreads();
    int h = u >> 8, c = u & 255;
    const float* w = att_w1 + ((size_t)(l * NH + h) * 512) * CDIM + c;
    float a0 = 0, a1 = 0, a2 = 0, a3 = 0;
    for (int z = 0; z < 512; ++z) {
        float wv = w[(size_t)z * CDIM];
        a0 += ps[0][z] * wv; a1 += ps[1][z] * wv;
        a2 += ps[2][z] * wv; a3 += ps[3][z] * wv;
    }
    float* rp = RT + ((size_t)h * CDIM + c) * TDIM + d0;
    rp[0] = a0; rp[1] = a1; rp[2] = a2; rp[3] = a3;
}

// v[b,h,j,d] = x[b,j] @ val_w. 2 rows/block.
__global__ void k_v(const float* __restrict__ x, const float* __restrict__ val_w,
                    int l, float* __restrict__ vbuf) {
    int bi0 = blockIdx.x * 2;
    int b = bi0 >> 8;
    int j0 = bi0 & 255;
    int t = threadIdx.x;           // 256
    __shared__ float xs[2][CDIM];
    for (int q = t; q < 2 * CDIM; q += 256) xs[q >> 8][q & 255] = x[bi0 * CDIM + q];
    __syncthreads();
    int h = t >> 6, d = t & 63;
    const float* w = val_w + ((size_t)(l * NH + h) * CDIM) * DHS + d;
    float a0 = 0, a1 = 0;
    for (int c = 0; c < CDIM; ++c) {
        float wv = w[(size_t)c * DHS];
        a0 += xs[0][c] * wv; a1 += xs[1][c] * wv;
    }
    float* vp = vbuf + ((size_t)(b * NH + h) * TDIM + j0) * DHS + d;
    vp[0 * DHS] = a0; vp[1 * DHS] = a1;
}

// wei[b,h,i,j] = softmax_j over causal triangle of gelu-dot logits.
__global__ void k_wei(const float* __restrict__ PT, const float* __restrict__ Qb,
                      const float* __restrict__ RT, const float* __restrict__ att_w2,
                      const float* __restrict__ att_b2, int l, float* __restrict__ wei) {
    int bid = blockIdx.x;
    int i = bid & 255;
    int h = (bid >> 8) & (NH - 1);
    int b = bid >> 10;
    int t = threadIdx.x;           // j, 256
    __shared__ float qs[CDIM];
    __shared__ float w2s[CDIM];
    __shared__ float red[TDIM];
    qs[t]  = Qb[((b * TDIM + i) * NH + h) * CDIM + t];
    w2s[t] = att_w2[(l * NH + h) * CDIM + t];
    __syncthreads();
    float acc = 0.f;
    if (t <= i) {
        const float* pp = PT + ((size_t)(b * NH + h) * CDIM) * TDIM + t;
        const float* rr = RT + ((size_t)h * CDIM) * TDIM + (i - t);
        for (int c = 0; c < CDIM; ++c) {
            float z = pp[(size_t)c * TDIM] + qs[c] + rr[(size_t)c * TDIM];
            acc += gelu_f(z) * w2s[c];
        }
    }
    float logit = (acc + att_b2[l * NH + h]) * 0.0625f;  // scale = C^-0.5
    red[t] = (t <= i) ? logit : -1e30f;
    __syncthreads();
    for (int s = 128; s > 0; s >>= 1) { if (t < s) red[t] = fmaxf(red[t], red[t + s]); __syncthreads(); }
    float mx = red[0]; __syncthreads();
    float e = (t <= i) ? __expf(logit - mx) : 0.f;
    red[t] = e; __syncthreads();
    for (int s = 128; s > 0; s >>= 1) { if (t < s) red[t] += red[t + s]; __syncthreads(); }
    float inv = 1.f / red[0];
    if (t <= i) wei[((size_t)(b * NH + h) * TDIM + i) * TDIM + t] = e * inv;
}

// attn[b,i,h*64+d] = sum_{j<=i} wei * v. 4 j-strip waves + LDS reduce.
__global__ void k_av(const float* __restrict__ wei, const float* __restrict__ vbuf,
                     float* __restrict__ attn) {
    int bid = blockIdx.x;
    int i = bid & 255;
    int h = (bid >> 8) & (NH - 1);
    int b = bid >> 10;
    int t = threadIdx.x;           // 256
    int s = t >> 6;                // j-strip
    int d = t & 63;
    __shared__ float part[4][DHS];
    const float* wrow = wei + ((size_t)(b * NH + h) * TDIM + i) * TDIM;
    const float* vp = vbuf + ((size_t)(b * NH + h) * TDIM) * DHS + d;
    float acc = 0.f;
    int jend = min(i + 1, (s + 1) * 64);
    for (int j = s * 64; j < jend; ++j) acc += wrow[j] * vp[(size_t)j * DHS];
    part[s][d] = acc;
    __syncthreads();
    if (t < DHS) {
        float r = part[0][t] + part[1][t] + part[2][t] + part[3][t];
        attn[(b * TDIM + i) * CDIM + h * DHS + t] = r;
    }
}

// x += attn @ proj_w + proj_b. 2 rows/block.
__global__ void k_proj(const float* __restrict__ attn, const float* __restrict__ proj_w,
                       const float* __restrict__ proj_b, int l, float* __restrict__ x) {
    int bi0 = blockIdx.x * 2;
    int t = threadIdx.x;           // 256
    __shared__ float as[2][CDIM];
    for (int q = t; q < 2 * CDIM; q += 256) as[q >> 8][q & 255] = attn[bi0 * CDIM + q];
    __syncthreads();
    const float* w = proj_w + (size_t)l * CDIM * CDIM + t;
    float bb = proj_b[l * CDIM + t];
    float a0 = bb, a1 = bb;
    for (int z = 0; z < CDIM; ++z) {
        float wv = w[(size_t)z * CDIM];
        a0 += as[0][z] * wv; a1 += as[1][z] * wv;
    }
    x[(bi0 + 0) * CDIM + t] += a0; x[(bi0 + 1) * CDIM + t] += a1;
}

// out[row] = LN(in[row]) * g + b, C=256.
__global__ void k_ln256(const float* __restrict__ x, const float* __restrict__ g,
                        const float* __restrict__ bb, float* __restrict__ out) {
    int bi = blockIdx.x;
    int t = threadIdx.x;           // 256
    __shared__ float red[CDIM];
    float val = x[bi * CDIM + t];
    red[t] = val; __syncthreads();
    for (int s = 128; s > 0; s >>= 1) { if (t < s) red[t] += red[t + s]; __syncthreads(); }
    float mean = red[0] * (1.f / 256.f); __syncthreads();
    float dv = val - mean;
    red[t] = dv * dv; __syncthreads();
    for (int s = 128; s > 0; s >>= 1) { if (t < s) red[t] += red[t + s]; __syncthreads(); }
    float r = rsqrtf(red[0] * (1.f / 256.f) + 1e-5f);
    out[bi * CDIM + t] = dv * r * g[t] + bb[t];
}

// final LN -> bf16
__global__ void k_lnf_bf16(const float* __restrict__ x, const float* __restrict__ g,
                           const float* __restrict__ bb, unsigned short* __restrict__ out) {
    int bi = blockIdx.x;
    int t = threadIdx.x;           // 256
    __shared__ float red[CDIM];
    float val = x[bi * CDIM + t];
    red[t] = val; __syncthreads();
    for (int s = 128; s > 0; s >>= 1) { if (t < s) red[t] += red[t + s]; __syncthreads(); }
    float mean = red[0] * (1.f / 256.f); __syncthreads();
    float dv = val - mean;
    red[t] = dv * dv; __syncthreads();
    for (int s = 128; s > 0; s >>= 1) { if (t < s) red[t] += red[t + s]; __syncthreads(); }
    float r = rsqrtf(red[0] * (1.f / 256.f) + 1e-5f);
    out[bi * CDIM + t] = f2bf(dv * r * g[t] + bb[t]);
}

// f = gelu(h @ ff_w1). 4 rows/block, u-slice across grid.y.
__global__ void k_ff1(const float* __restrict__ h, const float* __restrict__ ff_w1,
                      int l, float* __restrict__ f) {
    int bi0 = blockIdx.x * 4;
    int t = threadIdx.x;           // 512
    int u = blockIdx.y * 512 + t;  // 0..1023
    __shared__ float hs[4][CDIM];
    for (int q = t; q < 4 * CDIM; q += 512) hs[q >> 8][q & 255] = h[bi0 * CDIM + q];
    __syncthreads();
    const float* w = ff_w1 + (size_t)l * CDIM * FHID + u;
    float a0 = 0, a1 = 0, a2 = 0, a3 = 0;
    for (int c = 0; c < CDIM; ++c) {
        float wv = w[(size_t)c * FHID];
        a0 += hs[0][c] * wv; a1 += hs[1][c] * wv;
        a2 += hs[2][c] * wv; a3 += hs[3][c] * wv;
    }
    f[(bi0 + 0) * FHID + u] = gelu_f(a0);
    f[(bi0 + 1) * FHID + u] = gelu_f(a1);
    f[(bi0 + 2) * FHID + u] = gelu_f(a2);
    f[(bi0 + 3) * FHID + u] = gelu_f(a3);
}

// x += f @ ff_w2 + ff_b2. 2 rows/block.
__global__ void k_ff2(const float* __restrict__ f, const float* __restrict__ ff_w2,
                      const float* __restrict__ ff_b2, int l, float* __restrict__ x) {
    int bi0 = blockIdx.x * 2;
    int t = threadIdx.x;           // 256
    __shared__ float fs[2][FHID];
    for (int q = t; q < 2 * FHID; q += 256) fs[q >> 10][q & 1023] = f[bi0 * FHID + q];
    __syncthreads();
    const float* w = ff_w2 + (size_t)l * FHID * CDIM + t;
    float bb = ff_b2[l * CDIM + t];
    float a0 = bb, a1 = bb;
    for (int u = 0; u < FHID; ++u) {
        float wv = w[(size_t)u * CDIM];
        a0 += fs[0][u] * wv; a1 += fs[1][u] * wv;
    }
    x[(bi0 + 0) * CDIM + t] += a0; x[(bi0 + 1) * CDIM + t] += a1;
}

// head_w [256][8000] f32 -> wT [8000][256] bf16 (transpose + cast)
__global__ void k_wcast(const float* __restrict__ w, unsigned short* __restrict__ wT) {
    __shared__ float tile[32][33];
    int n0 = blockIdx.x * 32;   // 250
    int k0 = blockIdx.y * 32;   // 8
    int t = threadIdx.x;        // 256
    #pragma unroll
    for (int e = 0; e < 4; ++e) {
        int lin = e * 256 + t;
        int kk = lin >> 5, nn = lin & 31;
        tile[kk][nn] = w[(size_t)(k0 + kk) * NV + n0 + nn];
    }
    __syncthreads();
    #pragma unroll
    for (int e = 0; e < 4; ++e) {
        int lin = e * 256 + t;
        int nn = lin >> 5, kk = lin & 31;
        wT[(size_t)(n0 + nn) * CDIM + k0 + kk] = f2bf(tile[kk][nn]);
    }
}

// logits = xf_bf @ wT^T + head_b via MFMA. 64x64 tile, 4 waves of 2x2 16x16x32 frags.
__global__ __launch_bounds__(256) void k_head_mfma(
    const unsigned short* __restrict__ xf_bf,   // [512][256] bf16
    const unsigned short* __restrict__ wT,      // [8000][256] bf16
    const float* __restrict__ head_b,
    float* __restrict__ out)                    // [512][8000] f32
{
    __shared__ unsigned short A_lds[64 * 256];  // [m][k], XOR-swizzled
    __shared__ unsigned short B_lds[64 * 256];  // [n][k], XOR-swizzled
    int t = threadIdx.x;
    int r0 = blockIdx.x * 64;
    int n0 = blockIdx.y * 64;
    const uint4v* srcA = (const uint4v*)(xf_bf + (size_t)r0 * CDIM);
    const uint4v* srcB = (const uint4v*)(wT + (size_t)n0 * CDIM);
    #pragma unroll
    for (int it = 0; it < 8; ++it) {
        int chunk = it * 256 + t;       // 2048 x 16B chunks
        uint4v va = srcA[chunk];
        uint4v vb = srcB[chunk];
        int lin = chunk * 16;
        int row = lin >> 9;             // 512B per row
        int phys = lin ^ ((row & 7) << 4);
        *(uint4v*)((char*)A_lds + phys) = va;
        *(uint4v*)((char*)B_lds + phys) = vb;
    }
    __syncthreads();
    int lane = t & 63;
    int w = t >> 6;
    int wm = (w >> 1) * 32, wn = (w & 1) * 32;
    int l15 = lane & 15;
    int lk = (lane >> 4) * 8;           // k sub-offset
    f32x4 acc[2][2] = {};
    #pragma unroll
    for (int ks = 0; ks < 8; ++ks) {
        int kb = ks * 32 + lk;          // element-k
        bf16x8 a[2], b[2];
        #pragma unroll
        for (int f = 0; f < 2; ++f) {
            int m = wm + f * 16 + l15;
            int lina = m * 512 + kb * 2;
            a[f] = *(const bf16x8*)((const char*)A_lds + (lina ^ ((m & 7) << 4)));
            int n = wn + f * 16 + l15;
            int linb = n * 512 + kb * 2;
            b[f] = *(const bf16x8*)((const char*)B_lds + (linb ^ ((n & 7) << 4)));
        }
        acc[0][0] = __builtin_amdgcn_mfma_f32_16x16x32_bf16(a[0], b[0], acc[0][0], 0, 0, 0);
        acc[0][1] = __builtin_amdgcn_mfma_f32_16x16x32_bf16(a[0], b[1], acc[0][1], 0, 0, 0);
        acc[1][0] = __builtin_amdgcn_mfma_f32_16x16x32_bf16(a[1], b[0], acc[1][0], 0, 0, 0);
        acc[1][1] = __builtin_amdgcn_mfma_f32_16x16x32_bf16(a[1], b[1], acc[1][1], 0, 0, 0);
    }
    #pragma unroll
    for (int fm = 0; fm < 2; ++fm) {
        #pragma unroll
        for (int fn = 0; fn < 2; ++fn) {
            int col = n0 + wn + fn * 16 + l15;
            float hb = head_b[col];
            #pragma unroll
            for (int r = 0; r < 4; ++r) {
                int row = r0 + wm + fm * 16 + (lane >> 4) * 4 + r;
                out[(size_t)row * NV + col] = acc[fm][fn][r] + hb;
            }
        }
    }
}

extern "C" void kernel_launch(void* const* d_in, const int* in_sizes, int n_in,
                              void* d_out, int out_size, void* d_ws, size_t ws_size,
                              hipStream_t stream) {
    const int*   idx       = (const int*)  d_in[0];
    const float* tok_emb   = (const float*)d_in[1];
    const float* pos_table = (const float*)d_in[2];
    const float* pos_w1    = (const float*)d_in[3];
    const float* pos_w2    = (const float*)d_in[4];
    const float* pos_b2    = (const float*)d_in[5];
    const float* pos_ln_g  = (const float*)d_in[6];
    const float* pos_ln_b  = (const float*)d_in[7];
    const float* att_w1    = (const float*)d_in[8];
    const float* att_w2    = (const float*)d_in[9];
    const float* att_b2    = (const float*)d_in[10];
    const float* val_w     = (const float*)d_in[11];
    const float* proj_w    = (const float*)d_in[12];
    const float* proj_b    = (const float*)d_in[13];
    const float* ln2_g     = (const float*)d_in[14];
    const float* ln2_b     = (const float*)d_in[15];
    const float* ff_w1     = (const float*)d_in[16];
    const float* ff_w2     = (const float*)d_in[17];
    const float* ff_b2     = (const float*)d_in[18];
    const float* lnf_g     = (const float*)d_in[19];
    const float* lnf_b     = (const float*)d_in[20];
    const float* head_w    = (const float*)d_in[21];
    const float* head_b    = (const float*)d_in[22];
    float* out = (float*)d_out;

    float* ws = (float*)d_ws;
    float* x    = ws;  ws += NB * TDIM * CDIM;        // 131072
    float* peh  = ws;  ws += TDIM * 2 * CDIM;         // 131072
    float* ped  = ws;  ws += TDIM * 2 * CDIM;         // 131072
    float* PT   = ws;  ws += NB * NH * CDIM * TDIM;   // 524288
    float* Qb   = ws;  ws += NB * TDIM * NH * CDIM;   // 524288
    float* RT   = ws;  ws += NH * CDIM * TDIM;        // 262144
    float* vbuf = ws;  ws += NB * NH * TDIM * DHS;    // 131072
    float* wei  = ws;  ws += NB * NH * TDIM * TDIM;   // 524288
    float* attn = ws;  ws += NB * TDIM * CDIM;        // 131072
    float* hbuf = ws;  ws += NB * TDIM * CDIM;        // 131072
    float* fbuf = ws;  ws += NB * TDIM * FHID;        // 524288
    unsigned short* xf_bf = (unsigned short*)ws;      // 131072 ushort = 65536 floats
    ws += NB * TDIM * CDIM / 2;
    unsigned short* wT = (unsigned short*)ws;         // 8000*256 ushort = 1024000 floats
    ws += NV * CDIM / 2;
    // total ~17 MB

    // head_w transpose+cast (independent of everything else)
    {
        dim3 g(NV / 32, CDIM / 32);
        k_wcast<<<g, 256, 0, stream>>>(head_w, wT);
    }
    k_embed<<<NB * TDIM, CDIM, 0, stream>>>(idx, tok_emb, x);
    k_pe1<<<TDIM, 512, 0, stream>>>(pos_table, pos_w1, peh);
    k_pe2<<<TDIM, 512, 0, stream>>>(peh, pos_w2, pos_b2, pos_ln_g, pos_ln_b, ped);

    for (int l = 0; l < 2; ++l) {
        dim3 gpq(NB * TDIM / 4, 4);
        k_pq<<<gpq, 512, 0, stream>>>(x, att_w1, l, PT, Qb);
        dim3 gr(TDIM / 4, 2);
        k_r<<<gr, 512, 0, stream>>>(ped, att_w1, l, RT);
        k_v<<<NB * TDIM / 2, 256, 0, stream>>>(x, val_w, l, vbuf);
        k_wei<<<NB * NH * TDIM, 256, 0, stream>>>(PT, Qb, RT, att_w2, att_b2, l, wei);
        k_av<<<NB * NH * TDIM, 256, 0, stream>>>(wei, vbuf, attn);
        k_proj<<<NB * TDIM / 2, 256, 0, stream>>>(attn, proj_w, proj_b, l, x);
        k_ln256<<<NB * TDIM, 256, 0, stream>>>(x, ln2_g + l * CDIM, ln2_b + l * CDIM, hbuf);
        dim3 gf1(NB * TDIM / 4, 2);
        k_ff1<<<gf1, 512, 0, stream>>>(hbuf, ff_w1, l, fbuf);
        k_ff2<<<NB * TDIM / 2, 256, 0, stream>>>(fbuf, ff_w2, ff_b2, l, x);
    }

    k_lnf_bf16<<<NB * TDIM, 256, 0, stream>>>(x, lnf_g, lnf_b, xf_bf);
    dim3 hg(NB * TDIM / 64, NV / 64);   // (8, 125)
    k_head_mfma<<<hg, 256, 0, stream>>>(xf_bf, wT, head_b, out);
}

// Round 3
// 577.114 us; speedup vs baseline: 1.6404x; 1.0621x over previous
//
#include <hip/hip_runtime.h>
#include <hip/hip_bf16.h>
#include <math.h>

// Problem dims (fixed)
constexpr int TDIM = 256;   // sequence length t
constexpr int CDIM = 256;   // channels C
constexpr int NH   = 4;     // heads
constexpr int DHS  = 64;    // head size
constexpr int FHID = 1024;  // ffn hidden
constexpr int NV   = 8000;  // vocab
constexpr int NB   = 2;     // batch

typedef __attribute__((ext_vector_type(8))) short bf16x8;
typedef __attribute__((ext_vector_type(4))) float f32x4;
typedef __attribute__((ext_vector_type(4))) unsigned int uint4v;

__device__ __forceinline__ float gelu_f(float x) {
    return 0.5f * x * (1.0f + erff(x * 0.70710678118654752440f));
}

// tanh-form gelu: x*E/(E+1), E = exp2(x*(kA + kB*x^2)). ~9 VALU ops, 2 native trans.
__device__ __forceinline__ float gelu_fast(float x) {
    constexpr float kA = 2.0f * 1.4426950408889634f * 0.7978845608028654f;
    constexpr float kB = kA * 0.044715f;
    x = fminf(fmaxf(x, -30.f), 30.f);
    float e = exp2f(x * (kA + kB * x * x));
    return x * e * __builtin_amdgcn_rcpf(e + 1.0f);
}

__device__ __forceinline__ unsigned short f2bf(float f) {
    unsigned int u = __float_as_uint(f);
    unsigned int r = (u + 0x7FFF + ((u >> 16) & 1)) >> 16;   // RNE
    return (unsigned short)r;
}

// x[b,t,:] = tok_emb[idx[b,t]]
__global__ void k_embed(const int* __restrict__ idx, const float* __restrict__ tok_emb,
                        float* __restrict__ x) {
    int bt = blockIdx.x;           // 0..511
    int c  = threadIdx.x;          // 256
    int tok = idx[bt];
    x[bt * CDIM + c] = tok_emb[(size_t)tok * CDIM + c];
}

// fused pe: ped[d,:512] = LN(gelu(pos_table[d]@pos_w1) @ pos_w2 + pos_b2)
__global__ void k_pe(const float* __restrict__ pos_table, const float* __restrict__ pos_w1,
                     const float* __restrict__ pos_w2, const float* __restrict__ pos_b2,
                     const float* __restrict__ g, const float* __restrict__ bb,
                     float* __restrict__ ped) {
    int d = blockIdx.x;
    int t = threadIdx.x;           // 512
    __shared__ float xs[CDIM];
    __shared__ float hs[512];
    __shared__ float red[512];
    if (t < CDIM) xs[t] = pos_table[d * CDIM + t];
    __syncthreads();
    float acc = 0.f;
    for (int c = 0; c < CDIM; ++c) acc += xs[c] * pos_w1[(size_t)c * 512 + t];
    hs[t] = gelu_f(acc);
    __syncthreads();
    float acc2 = pos_b2[t];
    for (int z = 0; z < 512; ++z) acc2 += hs[z] * pos_w2[(size_t)z * 512 + t];
    red[t] = acc2; __syncthreads();
    for (int s = 256; s > 0; s >>= 1) { if (t < s) red[t] += red[t + s]; __syncthreads(); }
    float mean = red[0] * (1.f / 512.f); __syncthreads();
    float dv = acc2 - mean;
    red[t] = dv * dv; __syncthreads();
    for (int s = 256; s > 0; s >>= 1) { if (t < s) red[t] += red[t + s]; __syncthreads(); }
    float r = rsqrtf(red[0] * (1.f / 512.f) + 1e-5f);
    ped[d * 512 + t] = dv * r * g[t] + bb[t];
}

// P_T[b,h,c,j]; Q[b,i,h,c]. 4 rows/block, u-slice across grid.y.
__global__ void k_pq(const float* __restrict__ x, const float* __restrict__ att_w1,
                     int l, float* __restrict__ PT, float* __restrict__ Qb) {
    int bi0 = blockIdx.x * 4;
    int b = bi0 >> 8;
    int j0 = bi0 & 255;
    int t = threadIdx.x;           // 512
    int u = blockIdx.y * 512 + t;  // 0..2047
    __shared__ float xs[4][CDIM];
    for (int q = t; q < 4 * CDIM; q += 512) xs[q >> 8][q & 255] = x[bi0 * CDIM + q];
    __syncthreads();
    int isQ = u >> 10;
    int hc = u & 1023;
    int h = hc >> 8, c = hc & 255;
    const float* w = att_w1 + ((size_t)((l * NH + h) * 512 + isQ * 256)) * CDIM + c;
    float a0 = 0, a1 = 0, a2 = 0, a3 = 0;
    for (int z = 0; z < CDIM; ++z) {
        float wv = w[(size_t)z * CDIM];
        a0 += xs[0][z] * wv; a1 += xs[1][z] * wv;
        a2 += xs[2][z] * wv; a3 += xs[3][z] * wv;
    }
    if (isQ) {
        Qb[((bi0 + 0) * NH + h) * CDIM + c] = a0;
        Qb[((bi0 + 1) * NH + h) * CDIM + c] = a1;
        Qb[((bi0 + 2) * NH + h) * CDIM + c] = a2;
        Qb[((bi0 + 3) * NH + h) * CDIM + c] = a3;
    } else {
        float* p = PT + ((size_t)(b * NH + h) * CDIM + c) * TDIM + j0;
        p[0] = a0; p[1] = a1; p[2] = a2; p[3] = a3;
    }
}

// R_T[h,c,d] = ped[d] @ W1[h,:,c]. 4 d/block, u-slice across grid.y.
__global__ void k_r(const float* __restrict__ ped, const float* __restrict__ att_w1,
                    int l, float* __restrict__ RT) {
    int d0 = blockIdx.x * 4;
    int t = threadIdx.x;           // 512
    int u = blockIdx.y * 512 + t;  // 0..1023
    __shared__ float ps[4][512];
    for (int q = t; q < 2048; q += 512) ps[q >> 9][q & 511] = ped[d0 * 512 + q];
    __syncthreads();
    int h = u >> 8, c = u & 255;
    const float* w = att_w1 + ((size_t)(l * NH + h) * 512) * CDIM + c;
    float a0 = 0, a1 = 0, a2 = 0, a3 = 0;
    for (int z = 0; z < 512; ++z) {
        float wv = w[(size_t)z * CDIM];
        a0 += ps[0][z] * wv; a1 += ps[1][z] * wv;
        a2 += ps[2][z] * wv; a3 += ps[3][z] * wv;
    }
    float* rp = RT + ((size_t)h * CDIM + c) * TDIM + d0;
    rp[0] = a0; rp[1] = a1; rp[2] = a2; rp[3] = a3;
}

// v[b,h,j,d] = x[b,j] @ val_w. 2 rows/block.
__global__ void k_v(const float* __restrict__ x, const float* __restrict__ val_w,
                    int l, float* __restrict__ vbuf) {
    int bi0 = blockIdx.x * 2;
    int b = bi0 >> 8;
    int j0 = bi0 & 255;
    int t = threadIdx.x;           // 256
    __shared__ float xs[2][CDIM];
    for (int q = t; q < 2 * CDIM; q += 256) xs[q >> 8][q & 255] = x[bi0 * CDIM + q];
    __syncthreads();
    int h = t >> 6, d = t & 63;
    const float* w = val_w + ((size_t)(l * NH + h) * CDIM) * DHS + d;
    float a0 = 0, a1 = 0;
    for (int c = 0; c < CDIM; ++c) {
        float wv = w[(size_t)c * DHS];
        a0 += xs[0][c] * wv; a1 += xs[1][c] * wv;
    }
    float* vp = vbuf + ((size_t)(b * NH + h) * TDIM + j0) * DHS + d;
    vp[0 * DHS] = a0; vp[1 * DHS] = a1;
}

// wei rows for an i-tile of 4. block=(b,h,itile), thread=j. Wave-per-row softmax.
__global__ __launch_bounds__(256) void k_wei(
    const float* __restrict__ PT, const float* __restrict__ Qb,
    const float* __restrict__ RT, const float* __restrict__ att_w2,
    const float* __restrict__ att_b2, int l, float* __restrict__ wei) {
    int bid = blockIdx.x;          // 512
    int bh = bid & 7;
    int b = bh >> 2, h = bh & 3;
    int i0 = (63 - (bid >> 3)) * 4;   // descending size: biggest tiles dispatched first
    int t = threadIdx.x;           // j
    int j = t;
    __shared__ float sh[5][256];   // [0..3]=Q rows (later logits), [4]=w2
    for (int q = t; q < 4 * 256; q += 256) {
        int ii = q >> 8, c = q & 255;
        sh[ii][c] = Qb[((b * TDIM + (i0 + ii)) * NH + h) * CDIM + c];
    }
    sh[4][t] = att_w2[(l * NH + h) * CDIM + t];
    __syncthreads();
    float b2 = att_b2[l * NH + h];
    float acc0 = 0, acc1 = 0, acc2 = 0, acc3 = 0;
    int m = i0 - j;
    bool v0 = (m + 0) >= 0, v1 = (m + 1) >= 0, v2 = (m + 2) >= 0, v3 = (m + 3) >= 0;
    if ((t & ~63) <= i0 + 3) {     // wave-uniform skip of fully-masked waves
        const float* pp = PT + ((size_t)(b * NH + h) * CDIM) * TDIM + j;
        const float* rr = RT + ((size_t)h * CDIM) * TDIM + m;
        #pragma unroll 4
        for (int c = 0; c < 256; ++c) {
            float p = pp[(size_t)c * TDIM];
            float w2v = sh[4][c];
            float r0v = v0 ? rr[(size_t)c * TDIM + 0] : 0.f;
            float r1v = v1 ? rr[(size_t)c * TDIM + 1] : 0.f;
            float r2v = v2 ? rr[(size_t)c * TDIM + 2] : 0.f;
            float r3v = v3 ? rr[(size_t)c * TDIM + 3] : 0.f;
            acc0 = fmaf(gelu_fast(p + sh[0][c] + r0v), w2v, acc0);
            acc1 = fmaf(gelu_fast(p + sh[1][c] + r1v), w2v, acc1);
            acc2 = fmaf(gelu_fast(p + sh[2][c] + r2v), w2v, acc2);
            acc3 = fmaf(gelu_fast(p + sh[3][c] + r3v), w2v, acc3);
        }
    }
    __syncthreads();
    sh[0][j] = acc0; sh[1][j] = acc1; sh[2][j] = acc2; sh[3][j] = acc3;
    __syncthreads();
    int lane = t & 63, w = t >> 6;
    int i = i0 + w;
    float lv[4];
    #pragma unroll
    for (int s = 0; s < 4; ++s) {
        int jj = lane + s * 64;
        lv[s] = (jj <= i) ? (sh[w][jj] + b2) * 0.0625f : -1e30f;
    }
    float mx = fmaxf(fmaxf(lv[0], lv[1]), fmaxf(lv[2], lv[3]));
    #pragma unroll
    for (int off = 32; off; off >>= 1) mx = fmaxf(mx, __shfl_xor(mx, off));
    float es[4], sum = 0.f;
    #pragma unroll
    for (int s = 0; s < 4; ++s) { es[s] = exp2f((lv[s] - mx) * 1.4426950409f); sum += es[s]; }
    #pragma unroll
    for (int off = 32; off; off >>= 1) sum += __shfl_xor(sum, off);
    float inv = 1.0f / sum;
    float* wrow = wei + ((size_t)(b * NH + h) * TDIM + i) * TDIM;
    #pragma unroll
    for (int s = 0; s < 4; ++s) wrow[lane + s * 64] = es[s] * inv;
}

// attn[b,i,h*64+d] = sum_{j<=i} wei * v. 4 j-strip waves + LDS reduce.
__global__ void k_av(const float* __restrict__ wei, const float* __restrict__ vbuf,
                     float* __restrict__ attn) {
    int bid = blockIdx.x;
    int i = bid & 255;
    int h = (bid >> 8) & (NH - 1);
    int b = bid >> 10;
    int t = threadIdx.x;           // 256
    int s = t >> 6;                // j-strip
    int d = t & 63;
    __shared__ float part[4][DHS];
    const float* wrow = wei + ((size_t)(b * NH + h) * TDIM + i) * TDIM;
    const float* vp = vbuf + ((size_t)(b * NH + h) * TDIM) * DHS + d;
    float acc = 0.f;
    int jend = min(i + 1, (s + 1) * 64);
    for (int j = s * 64; j < jend; ++j) acc += wrow[j] * vp[(size_t)j * DHS];
    part[s][d] = acc;
    __syncthreads();
    if (t < DHS) {
        float r = part[0][t] + part[1][t] + part[2][t] + part[3][t];
        attn[(b * TDIM + i) * CDIM + h * DHS + t] = r;
    }
}

// fused: x += attn@proj_w + proj_b;  hbuf = LN(x). 2 rows/block.
__global__ void k_proj_ln(const float* __restrict__ attn, const float* __restrict__ proj_w,
                          const float* __restrict__ proj_b, int l, float* __restrict__ x,
                          const float* __restrict__ lg, const float* __restrict__ lb,
                          float* __restrict__ hbuf) {
    int bi0 = blockIdx.x * 2;
    int t = threadIdx.x;           // 256
    __shared__ float as[2][CDIM];
    __shared__ float rA[CDIM], rB[CDIM];
    for (int q = t; q < 2 * CDIM; q += 256) as[q >> 8][q & 255] = attn[bi0 * CDIM + q];
    __syncthreads();
    const float* w = proj_w + (size_t)l * CDIM * CDIM + t;
    float bb = proj_b[l * CDIM + t];
    float a0 = bb, a1 = bb;
    for (int z = 0; z < CDIM; ++z) {
        float wv = w[(size_t)z * CDIM];
        a0 += as[0][z] * wv; a1 += as[1][z] * wv;
    }
    float xn0 = x[(bi0 + 0) * CDIM + t] + a0;
    float xn1 = x[(bi0 + 1) * CDIM + t] + a1;
    x[(bi0 + 0) * CDIM + t] = xn0;
    x[(bi0 + 1) * CDIM + t] = xn1;
    rA[t] = xn0; rB[t] = xn1; __syncthreads();
    for (int s = 128; s > 0; s >>= 1) { if (t < s) { rA[t] += rA[t + s]; rB[t] += rB[t + s]; } __syncthreads(); }
    float mu0 = rA[0] * (1.f / 256.f), mu1 = rB[0] * (1.f / 256.f); __syncthreads();
    float d0 = xn0 - mu0, d1 = xn1 - mu1;
    rA[t] = d0 * d0; rB[t] = d1 * d1; __syncthreads();
    for (int s = 128; s > 0; s >>= 1) { if (t < s) { rA[t] += rA[t + s]; rB[t] += rB[t + s]; } __syncthreads(); }
    float r0 = rsqrtf(rA[0] * (1.f / 256.f) + 1e-5f);
    float r1 = rsqrtf(rB[0] * (1.f / 256.f) + 1e-5f);
    float gg = lg[t], bl = lb[t];
    hbuf[(bi0 + 0) * CDIM + t] = d0 * r0 * gg + bl;
    hbuf[(bi0 + 1) * CDIM + t] = d1 * r1 * gg + bl;
}

// final LN -> bf16
__global__ void k_lnf_bf16(const float* __restrict__ x, const float* __restrict__ g,
                           const float* __restrict__ bb, unsigned short* __restrict__ out) {
    int bi = blockIdx.x;
    int t = threadIdx.x;           // 256
    __shared__ float red[CDIM];
    float val = x[bi * CDIM + t];
    red[t] = val; __syncthreads();
    for (int s = 128; s > 0; s >>= 1) { if (t < s) red[t] += red[t + s]; __syncthreads(); }
    float mean = red[0] * (1.f / 256.f); __syncthreads();
    float dv = val - mean;
    red[t] = dv * dv; __syncthreads();
    for (int s = 128; s > 0; s >>= 1) { if (t < s) red[t] += red[t + s]; __syncthreads(); }
    float r = rsqrtf(red[0] * (1.f / 256.f) + 1e-5f);
    out[bi * CDIM + t] = f2bf(dv * r * g[t] + bb[t]);
}

// f = gelu(h @ ff_w1). 4 rows/block, u-slice across grid.y.
__global__ void k_ff1(const float* __restrict__ h, const float* __restrict__ ff_w1,
                      int l, float* __restrict__ f) {
    int bi0 = blockIdx.x * 4;
    int t = threadIdx.x;           // 512
    int u = blockIdx.y * 512 + t;  // 0..1023
    __shared__ float hs[4][CDIM];
    for (int q = t; q < 4 * CDIM; q += 512) hs[q >> 8][q & 255] = h[bi0 * CDIM + q];
    __syncthreads();
    const float* w = ff_w1 + (size_t)l * CDIM * FHID + u;
    float a0 = 0, a1 = 0, a2 = 0, a3 = 0;
    for (int c = 0; c < CDIM; ++c) {
        float wv = w[(size_t)c * FHID];
        a0 += hs[0][c] * wv; a1 += hs[1][c] * wv;
        a2 += hs[2][c] * wv; a3 += hs[3][c] * wv;
    }
    f[(bi0 + 0) * FHID + u] = gelu_f(a0);
    f[(bi0 + 1) * FHID + u] = gelu_f(a1);
    f[(bi0 + 2) * FHID + u] = gelu_f(a2);
    f[(bi0 + 3) * FHID + u] = gelu_f(a3);
}

// x += f @ ff_w2 + ff_b2. 2 rows/block.
__global__ void k_ff2(const float* __restrict__ f, const float* __restrict__ ff_w2,
                      const float* __restrict__ ff_b2, int l, float* __restrict__ x) {
    int bi0 = blockIdx.x * 2;
    int t = threadIdx.x;           // 256
    __shared__ float fs[2][FHID];
    for (int q = t; q < 2 * FHID; q += 256) fs[q >> 10][q & 1023] = f[bi0 * FHID + q];
    __syncthreads();
    const float* w = ff_w2 + (size_t)l * FHID * CDIM + t;
    float bb = ff_b2[l * CDIM + t];
    float a0 = bb, a1 = bb;
    for (int u = 0; u < FHID; ++u) {
        float wv = w[(size_t)u * CDIM];
        a0 += fs[0][u] * wv; a1 += fs[1][u] * wv;
    }
    x[(bi0 + 0) * CDIM + t] += a0; x[(bi0 + 1) * CDIM + t] += a1;
}

// head_w [256][8000] f32 -> wT [8000][256] bf16 (transpose + cast)
__global__ void k_wcast(const float* __restrict__ w, unsigned short* __restrict__ wT) {
    __shared__ float tile[32][33];
    int n0 = blockIdx.x * 32;
    int k0 = blockIdx.y * 32;
    int t = threadIdx.x;        // 256
    #pragma unroll
    for (int e = 0; e < 4; ++e) {
        int lin = e * 256 + t;
        int kk = lin >> 5, nn = lin & 31;
        tile[kk][nn] = w[(size_t)(k0 + kk) * NV + n0 + nn];
    }
    __syncthreads();
    #pragma unroll
    for (int e = 0; e < 4; ++e) {
        int lin = e * 256 + t;
        int nn = lin >> 5, kk = lin & 31;
        wT[(size_t)(n0 + nn) * CDIM + k0 + kk] = f2bf(tile[kk][nn]);
    }
}

// logits = xf_bf @ wT^T + head_b via MFMA. 64x64 tile, 4 waves of 2x2 16x16x32 frags.
__global__ __launch_bounds__(256) void k_head_mfma(
    const unsigned short* __restrict__ xf_bf,   // [512][256] bf16
    const unsigned short* __restrict__ wT,      // [8000][256] bf16
    const float* __restrict__ head_b,
    float* __restrict__ out)                    // [512][8000] f32
{
    __shared__ unsigned short A_lds[64 * 256];
    __shared__ unsigned short B_lds[64 * 256];
    int t = threadIdx.x;
    int r0 = blockIdx.x * 64;
    int n0 = blockIdx.y * 64;
    const uint4v* srcA = (const uint4v*)(xf_bf + (size_t)r0 * CDIM);
    const uint4v* srcB = (const uint4v*)(wT + (size_t)n0 * CDIM);
    #pragma unroll
    for (int it = 0; it < 8; ++it) {
        int chunk = it * 256 + t;
        uint4v va = srcA[chunk];
        uint4v vb = srcB[chunk];
        int lin = chunk * 16;
        int row = lin >> 9;
        int phys = lin ^ ((row & 7) << 4);
        *(uint4v*)((char*)A_lds + phys) = va;
        *(uint4v*)((char*)B_lds + phys) = vb;
    }
    __syncthreads();
    int lane = t & 63;
    int w = t >> 6;
    int wm = (w >> 1) * 32, wn = (w & 1) * 32;
    int l15 = lane & 15;
    int lk = (lane >> 4) * 8;
    f32x4 acc[2][2] = {};
    #pragma unroll
    for (int ks = 0; ks < 8; ++ks) {
        int kb = ks * 32 + lk;
        bf16x8 a[2], b[2];
        #pragma unroll
        for (int f = 0; f < 2; ++f) {
            int mrow = wm + f * 16 + l15;
            int lina = mrow * 512 + kb * 2;
            a[f] = *(const bf16x8*)((const char*)A_lds + (lina ^ ((mrow & 7) << 4)));
            int nrow = wn + f * 16 + l15;
            int linb = nrow * 512 + kb * 2;
            b[f] = *(const bf16x8*)((const char*)B_lds + (linb ^ ((nrow & 7) << 4)));
        }
        acc[0][0] = __builtin_amdgcn_mfma_f32_16x16x32_bf16(a[0], b[0], acc[0][0], 0, 0, 0);
        acc[0][1] = __builtin_amdgcn_mfma_f32_16x16x32_bf16(a[0], b[1], acc[0][1], 0, 0, 0);
        acc[1][0] = __builtin_amdgcn_mfma_f32_16x16x32_bf16(a[1], b[0], acc[1][0], 0, 0, 0);
        acc[1][1] = __builtin_amdgcn_mfma_f32_16x16x32_bf16(a[1], b[1], acc[1][1], 0, 0, 0);
    }
    #pragma unroll
    for (int fm = 0; fm < 2; ++fm) {
        #pragma unroll
        for (int fn = 0; fn < 2; ++fn) {
            int col = n0 + wn + fn * 16 + l15;
            float hb = head_b[col];
            #pragma unroll
            for (int r = 0; r < 4; ++r) {
                int row = r0 + wm + fm * 16 + (lane >> 4) * 4 + r;
                out[(size_t)row * NV + col] = acc[fm][fn][r] + hb;
            }
        }
    }
}

extern "C" void kernel_launch(void* const* d_in, const int* in_sizes, int n_in,
                              void* d_out, int out_size, void* d_ws, size_t ws_size,
                              hipStream_t stream) {
    const int*   idx       = (const int*)  d_in[0];
    const float* tok_emb   = (const float*)d_in[1];
    const float* pos_table = (const float*)d_in[2];
    const float* pos_w1    = (const float*)d_in[3];
    const float* pos_w2    = (const float*)d_in[4];
    const float* pos_b2    = (const float*)d_in[5];
    const float* pos_ln_g  = (const float*)d_in[6];
    const float* pos_ln_b  = (const float*)d_in[7];
    const float* att_w1    = (const float*)d_in[8];
    const float* att_w2    = (const float*)d_in[9];
    const float* att_b2    = (const float*)d_in[10];
    const float* val_w     = (const float*)d_in[11];
    const float* proj_w    = (const float*)d_in[12];
    const float* proj_b    = (const float*)d_in[13];
    const float* ln2_g     = (const float*)d_in[14];
    const float* ln2_b     = (const float*)d_in[15];
    const float* ff_w1     = (const float*)d_in[16];
    const float* ff_w2     = (const float*)d_in[17];
    const float* ff_b2     = (const float*)d_in[18];
    const float* lnf_g     = (const float*)d_in[19];
    const float* lnf_b     = (const float*)d_in[20];
    const float* head_w    = (const float*)d_in[21];
    const float* head_b    = (const float*)d_in[22];
    float* out = (float*)d_out;

    float* ws = (float*)d_ws;
    float* x    = ws;  ws += NB * TDIM * CDIM;
    float* ped  = ws;  ws += TDIM * 2 * CDIM;
    float* PT   = ws;  ws += NB * NH * CDIM * TDIM;
    float* Qb   = ws;  ws += NB * TDIM * NH * CDIM;
    float* RT   = ws;  ws += NH * CDIM * TDIM;
    float* vbuf = ws;  ws += NB * NH * TDIM * DHS;
    float* wei  = ws;  ws += NB * NH * TDIM * TDIM;
    float* attn = ws;  ws += NB * TDIM * CDIM;
    float* hbuf = ws;  ws += NB * TDIM * CDIM;
    float* fbuf = ws;  ws += NB * TDIM * FHID;
    unsigned short* xf_bf = (unsigned short*)ws;
    ws += NB * TDIM * CDIM / 2;
    unsigned short* wT = (unsigned short*)ws;
    ws += NV * CDIM / 2;

    {
        dim3 g(NV / 32, CDIM / 32);
        k_wcast<<<g, 256, 0, stream>>>(head_w, wT);
    }
    k_embed<<<NB * TDIM, CDIM, 0, stream>>>(idx, tok_emb, x);
    k_pe<<<TDIM, 512, 0, stream>>>(pos_table, pos_w1, pos_w2, pos_b2, pos_ln_g, pos_ln_b, ped);

    for (int l = 0; l < 2; ++l) {
        dim3 gpq(NB * TDIM / 4, 4);
        k_pq<<<gpq, 512, 0, stream>>>(x, att_w1, l, PT, Qb);
        dim3 gr(TDIM / 4, 2);
        k_r<<<gr, 512, 0, stream>>>(ped, att_w1, l, RT);
        k_v<<<NB * TDIM / 2, 256, 0, stream>>>(x, val_w, l, vbuf);
        k_wei<<<NB * NH * TDIM / 4, 256, 0, stream>>>(PT, Qb, RT, att_w2, att_b2, l, wei);
        k_av<<<NB * NH * TDIM, 256, 0, stream>>>(wei, vbuf, attn);
        k_proj_ln<<<NB * TDIM / 2, 256, 0, stream>>>(attn, proj_w, proj_b, l, x,
                                                     ln2_g + l * CDIM, ln2_b + l * CDIM, hbuf);
        dim3 gf1(NB * TDIM / 4, 2);
        k_ff1<<<gf1, 512, 0, stream>>>(hbuf, ff_w1, l, fbuf);
        k_ff2<<<NB * TDIM / 2, 256, 0, stream>>>(fbuf, ff_w2, ff_b2, l, x);
    }

    k_lnf_bf16<<<NB * TDIM, 256, 0, stream>>>(x, lnf_g, lnf_b, xf_bf);
    dim3 hg(NB * TDIM / 64, NV / 64);
    k_head_mfma<<<hg, 256, 0, stream>>>(xf_bf, wT, head_b, out);
}

// Round 4
// 422.396 us; speedup vs baseline: 2.2413x; 1.3663x over previous
//
#include <hip/hip_runtime.h>
#include <hip/hip_bf16.h>
#include <math.h>

// Problem dims (fixed)
constexpr int TDIM = 256;   // sequence length t
constexpr int CDIM = 256;   // channels C
constexpr int NH   = 4;     // heads
constexpr int DHS  = 64;    // head size
constexpr int FHID = 1024;  // ffn hidden
constexpr int NV   = 8000;  // vocab
constexpr int NB   = 2;     // batch

typedef __attribute__((ext_vector_type(8))) short bf16x8;
typedef __attribute__((ext_vector_type(4))) float f32x4;
typedef __attribute__((ext_vector_type(4))) unsigned int uint4v;

__device__ __forceinline__ float gelu_f(float x) {
    return 0.5f * x * (1.0f + erff(x * 0.70710678118654752440f));
}

// tanh-form gelu: x*E/(E+1), E = exp2(min(arg,120)). Correct asymptotes, no NaN.
__device__ __forceinline__ float gelu_fast(float x) {
    constexpr float kA = 2.0f * 1.4426950408889634f * 0.7978845608028654f;
    constexpr float kB = kA * 0.044715f;
    float arg = fminf(x * (kA + kB * x * x), 120.f);
    float e = exp2f(arg);
    return x * e * __builtin_amdgcn_rcpf(e + 1.0f);
}

__device__ __forceinline__ unsigned short f2bf(float f) {
    unsigned int u = __float_as_uint(f);
    unsigned int r = (u + 0x7FFF + ((u >> 16) & 1)) >> 16;   // RNE
    return (unsigned short)r;
}

// ---------------- generic transpose+cast: dst[c][r] = bf16(src[r][c]) ----------------
// grid (C/32, R/32, nslice), block 256. slice stride = R*C on both sides.
__global__ void k_tcast(const float* __restrict__ src, unsigned short* __restrict__ dst,
                        int R, int C) {
    size_t soff = (size_t)blockIdx.z * R * C;
    src += soff; dst += soff;
    __shared__ float tile[32][33];
    int c0 = blockIdx.x * 32, r0 = blockIdx.y * 32;
    int t = threadIdx.x;        // 256
    #pragma unroll
    for (int e = 0; e < 4; ++e) {
        int lin = e * 256 + t;
        int rr = lin >> 5, cc = lin & 31;
        tile[rr][cc] = src[(size_t)(r0 + rr) * C + c0 + cc];
    }
    __syncthreads();
    #pragma unroll
    for (int e = 0; e < 4; ++e) {
        int lin = e * 256 + t;
        int cc = lin >> 5, rr = lin & 31;
        dst[(size_t)(c0 + cc) * R + r0 + rr] = f2bf(tile[rr][cc]);
    }
}

// x[b,t,:] = tok_emb[idx[b,t]] (f32 + bf16 copies)
__global__ void k_embed(const int* __restrict__ idx, const float* __restrict__ tok_emb,
                        float* __restrict__ x, unsigned short* __restrict__ x_bf) {
    int bt = blockIdx.x;           // 0..511
    int c  = threadIdx.x;          // 256
    int tok = idx[bt];
    float v = tok_emb[(size_t)tok * CDIM + c];
    x[bt * CDIM + c] = v;
    x_bf[bt * CDIM + c] = f2bf(v);
}

// fused pe: ped_bf[d,:512] = bf16(LN(gelu(pos_table[d]@pos_w1) @ pos_w2 + pos_b2))
__global__ void k_pe(const float* __restrict__ pos_table, const float* __restrict__ pos_w1,
                     const float* __restrict__ pos_w2, const float* __restrict__ pos_b2,
                     const float* __restrict__ g, const float* __restrict__ bb,
                     unsigned short* __restrict__ ped_bf) {
    int d = blockIdx.x;
    int t = threadIdx.x;           // 512
    __shared__ float xs[CDIM];
    __shared__ float hs[512];
    __shared__ float red[512];
    if (t < CDIM) xs[t] = pos_table[d * CDIM + t];
    __syncthreads();
    float acc = 0.f;
    for (int c = 0; c < CDIM; ++c) acc += xs[c] * pos_w1[(size_t)c * 512 + t];
    hs[t] = gelu_f(acc);
    __syncthreads();
    float acc2 = pos_b2[t];
    for (int z = 0; z < 512; ++z) acc2 += hs[z] * pos_w2[(size_t)z * 512 + t];
    red[t] = acc2; __syncthreads();
    for (int s = 256; s > 0; s >>= 1) { if (t < s) red[t] += red[t + s]; __syncthreads(); }
    float mean = red[0] * (1.f / 512.f); __syncthreads();
    float dv = acc2 - mean;
    red[t] = dv * dv; __syncthreads();
    for (int s = 256; s > 0; s >>= 1) { if (t < s) red[t] += red[t + s]; __syncthreads(); }
    float r = rsqrtf(red[0] * (1.f / 512.f) + 1e-5f);
    ped_bf[d * 512 + t] = f2bf(dv * r * g[t] + bb[t]);
}

// ---------------- shared bf16 MFMA 64x64-tile core ----------------
// acc[2][2] += A_tile[64, kLen] @ B_tile[64, kLen]^T; A/B row-major with strides lda/ldb.
// kLen multiple of 256. 256 threads. LDS XOR-swizzle (T2) on write and read.
__device__ __forceinline__ void gemm64_core(
    const unsigned short* __restrict__ A, int lda,
    const unsigned short* __restrict__ B, int ldb,
    int kLen, int t, f32x4 acc[2][2],
    unsigned short* __restrict__ A_lds, unsigned short* __restrict__ B_lds)
{
    int lane = t & 63;
    int w = t >> 6;
    int wm = (w >> 1) * 32, wn = (w & 1) * 32;
    int l15 = lane & 15;
    int lk = (lane >> 4) * 8;
    for (int kc = 0; kc < kLen; kc += 256) {
        #pragma unroll
        for (int it = 0; it < 8; ++it) {
            int chunk = it * 256 + t;       // 2048 x 16B chunks
            int row = chunk >> 5;           // 32 chunks per 256-col row
            int c16 = chunk & 31;
            uint4v va = *(const uint4v*)(A + (size_t)row * lda + kc + c16 * 8);
            uint4v vb = *(const uint4v*)(B + (size_t)row * ldb + kc + c16 * 8);
            int lin = row * 512 + c16 * 16;
            int phys = lin ^ ((row & 7) << 4);
            *(uint4v*)((char*)A_lds + phys) = va;
            *(uint4v*)((char*)B_lds + phys) = vb;
        }
        __syncthreads();
        #pragma unroll
        for (int ks = 0; ks < 8; ++ks) {
            int kb = ks * 32 + lk;
            bf16x8 a[2], b[2];
            #pragma unroll
            for (int f = 0; f < 2; ++f) {
                int mrow = wm + f * 16 + l15;
                int lina = mrow * 512 + kb * 2;
                a[f] = *(const bf16x8*)((const char*)A_lds + (lina ^ ((mrow & 7) << 4)));
                int nrow = wn + f * 16 + l15;
                int linb = nrow * 512 + kb * 2;
                b[f] = *(const bf16x8*)((const char*)B_lds + (linb ^ ((nrow & 7) << 4)));
            }
            acc[0][0] = __builtin_amdgcn_mfma_f32_16x16x32_bf16(a[0], b[0], acc[0][0], 0, 0, 0);
            acc[0][1] = __builtin_amdgcn_mfma_f32_16x16x32_bf16(a[0], b[1], acc[0][1], 0, 0, 0);
            acc[1][0] = __builtin_amdgcn_mfma_f32_16x16x32_bf16(a[1], b[0], acc[1][0], 0, 0, 0);
            acc[1][1] = __builtin_amdgcn_mfma_f32_16x16x32_bf16(a[1], b[1], acc[1][1], 0, 0, 0);
        }
        __syncthreads();
    }
}

// pq GEMM: out[512, 2048] = x_bf @ W1 (via W1r with isQ half-offset); scatter to PT/Qb.
// grid (8, 32), 256 threads.
__global__ __launch_bounds__(256) void k_pq_gemm(
    const unsigned short* __restrict__ x_bf,   // [512][256]
    const unsigned short* __restrict__ W1r,    // [L][1024][512]: [h*256+c][z]
    float* __restrict__ PT, float* __restrict__ Qb, int l)
{
    __shared__ unsigned short A_lds[64 * 256];
    __shared__ unsigned short B_lds[64 * 256];
    int t = threadIdx.x;
    int r0 = blockIdx.x * 64;
    int n0 = blockIdx.y * 64;                  // output col tile 0..2047
    int h = n0 >> 9, isQ = (n0 >> 8) & 1;
    const unsigned short* Bp = W1r + (size_t)l * 1024 * 512
                             + (size_t)(h * 256 + (n0 & 255)) * 512 + isQ * 256;
    f32x4 acc[2][2] = {};
    gemm64_core(x_bf + (size_t)r0 * 256, 256, Bp, 512, 256, t, acc, A_lds, B_lds);
    int lane = t & 63, w = t >> 6;
    int wm = (w >> 1) * 32, wn = (w & 1) * 32;
    int l15 = lane & 15;
    #pragma unroll
    for (int fm = 0; fm < 2; ++fm) {
        #pragma unroll
        for (int fn = 0; fn < 2; ++fn) {
            int col = n0 + wn + fn * 16 + l15;
            int c = col & 255;
            #pragma unroll
            for (int r = 0; r < 4; ++r) {
                int row = r0 + wm + fm * 16 + (lane >> 4) * 4 + r;
                int b = row >> 8, ij = row & 255;
                if (isQ) Qb[((b * TDIM + ij) * NH + h) * CDIM + c] = acc[fm][fn][r];
                else     PT[((size_t)(b * NH + h) * CDIM + c) * TDIM + ij] = acc[fm][fn][r];
            }
        }
    }
}

// r GEMM: out[256 d, 1024 (h,c)] = ped_bf @ W1r^T; RT[col*256 + d]. grid (4, 16).
__global__ __launch_bounds__(256) void k_r_gemm(
    const unsigned short* __restrict__ ped_bf, // [256][512]
    const unsigned short* __restrict__ W1r,    // [L][1024][512]
    float* __restrict__ RT, int l)
{
    __shared__ unsigned short A_lds[64 * 256];
    __shared__ unsigned short B_lds[64 * 256];
    int t = threadIdx.x;
    int r0 = blockIdx.x * 64;
    int n0 = blockIdx.y * 64;
    const unsigned short* Bp = W1r + (size_t)l * 1024 * 512 + (size_t)n0 * 512;
    f32x4 acc[2][2] = {};
    gemm64_core(ped_bf + (size_t)r0 * 512, 512, Bp, 512, 512, t, acc, A_lds, B_lds);
    int lane = t & 63, w = t >> 6;
    int wm = (w >> 1) * 32, wn = (w & 1) * 32;
    int l15 = lane & 15;
    #pragma unroll
    for (int fm = 0; fm < 2; ++fm) {
        #pragma unroll
        for (int fn = 0; fn < 2; ++fn) {
            int col = n0 + wn + fn * 16 + l15;
            #pragma unroll
            for (int r = 0; r < 4; ++r) {
                int d = r0 + wm + fm * 16 + (lane >> 4) * 4 + r;
                RT[(size_t)col * TDIM + d] = acc[fm][fn][r];
            }
        }
    }
}

// ff1 GEMM: fbuf_bf[512,1024] = bf16(gelu(hbuf_bf @ Wff1^T)). grid (8, 16).
__global__ __launch_bounds__(256) void k_ff1_gemm(
    const unsigned short* __restrict__ hbuf_bf, // [512][256]
    const unsigned short* __restrict__ Wff1,    // [L][1024][256]
    unsigned short* __restrict__ fbuf_bf, int l)
{
    __shared__ unsigned short A_lds[64 * 256];
    __shared__ unsigned short B_lds[64 * 256];
    int t = threadIdx.x;
    int r0 = blockIdx.x * 64;
    int n0 = blockIdx.y * 64;
    const unsigned short* Bp = Wff1 + (size_t)l * 1024 * 256 + (size_t)n0 * 256;
    f32x4 acc[2][2] = {};
    gemm64_core(hbuf_bf + (size_t)r0 * 256, 256, Bp, 256, 256, t, acc, A_lds, B_lds);
    int lane = t & 63, w = t >> 6;
    int wm = (w >> 1) * 32, wn = (w & 1) * 32;
    int l15 = lane & 15;
    #pragma unroll
    for (int fm = 0; fm < 2; ++fm) {
        #pragma unroll
        for (int fn = 0; fn < 2; ++fn) {
            int col = n0 + wn + fn * 16 + l15;
            #pragma unroll
            for (int r = 0; r < 4; ++r) {
                int row = r0 + wm + fm * 16 + (lane >> 4) * 4 + r;
                fbuf_bf[(size_t)row * FHID + col] = f2bf(gelu_f(acc[fm][fn][r]));
            }
        }
    }
}

// ff2 GEMM: x += fbuf_bf @ Wff2^T + b2; writes x f32 + x_bf. grid (8, 4). K=1024.
__global__ __launch_bounds__(256) void k_ff2_gemm(
    const unsigned short* __restrict__ fbuf_bf, // [512][1024]
    const unsigned short* __restrict__ Wff2,    // [L][256][1024]
    const float* __restrict__ ff_b2,
    float* __restrict__ x, unsigned short* __restrict__ x_bf, int l)
{
    __shared__ unsigned short A_lds[64 * 256];
    __shared__ unsigned short B_lds[64 * 256];
    int t = threadIdx.x;
    int r0 = blockIdx.x * 64;
    int n0 = blockIdx.y * 64;
    const unsigned short* Bp = Wff2 + (size_t)l * 256 * 1024 + (size_t)n0 * 1024;
    f32x4 acc[2][2] = {};
    gemm64_core(fbuf_bf + (size_t)r0 * 1024, 1024, Bp, 1024, 1024, t, acc, A_lds, B_lds);
    int lane = t & 63, w = t >> 6;
    int wm = (w >> 1) * 32, wn = (w & 1) * 32;
    int l15 = lane & 15;
    #pragma unroll
    for (int fm = 0; fm < 2; ++fm) {
        #pragma unroll
        for (int fn = 0; fn < 2; ++fn) {
            int col = n0 + wn + fn * 16 + l15;
            float bb = ff_b2[l * CDIM + col];
            #pragma unroll
            for (int r = 0; r < 4; ++r) {
                int row = r0 + wm + fm * 16 + (lane >> 4) * 4 + r;
                float v = x[(size_t)row * CDIM + col] + acc[fm][fn][r] + bb;
                x[(size_t)row * CDIM + col] = v;
                x_bf[(size_t)row * CDIM + col] = f2bf(v);
            }
        }
    }
}

// head GEMM: out[512,8000] = xf_bf @ wT^T + head_b. grid (8, 125).
__global__ __launch_bounds__(256) void k_head_mfma(
    const unsigned short* __restrict__ xf_bf,   // [512][256]
    const unsigned short* __restrict__ wT,      // [8000][256]
    const float* __restrict__ head_b,
    float* __restrict__ out)
{
    __shared__ unsigned short A_lds[64 * 256];
    __shared__ unsigned short B_lds[64 * 256];
    int t = threadIdx.x;
    int r0 = blockIdx.x * 64;
    int n0 = blockIdx.y * 64;
    f32x4 acc[2][2] = {};
    gemm64_core(xf_bf + (size_t)r0 * 256, 256, wT + (size_t)n0 * 256, 256, 256,
                t, acc, A_lds, B_lds);
    int lane = t & 63, w = t >> 6;
    int wm = (w >> 1) * 32, wn = (w & 1) * 32;
    int l15 = lane & 15;
    #pragma unroll
    for (int fm = 0; fm < 2; ++fm) {
        #pragma unroll
        for (int fn = 0; fn < 2; ++fn) {
            int col = n0 + wn + fn * 16 + l15;
            float hb = head_b[col];
            #pragma unroll
            for (int r = 0; r < 4; ++r) {
                int row = r0 + wm + fm * 16 + (lane >> 4) * 4 + r;
                out[(size_t)row * NV + col] = acc[fm][fn][r] + hb;
            }
        }
    }
}

// v[b,h,j,d] = x[b,j] @ val_w. 2 rows/block.
__global__ void k_v(const float* __restrict__ x, const float* __restrict__ val_w,
                    int l, float* __restrict__ vbuf) {
    int bi0 = blockIdx.x * 2;
    int b = bi0 >> 8;
    int j0 = bi0 & 255;
    int t = threadIdx.x;           // 256
    __shared__ float xs[2][CDIM];
    for (int q = t; q < 2 * CDIM; q += 256) xs[q >> 8][q & 255] = x[bi0 * CDIM + q];
    __syncthreads();
    int h = t >> 6, d = t & 63;
    const float* w = val_w + ((size_t)(l * NH + h) * CDIM) * DHS + d;
    float a0 = 0, a1 = 0;
    for (int c = 0; c < CDIM; ++c) {
        float wv = w[(size_t)c * DHS];
        a0 += xs[0][c] * wv; a1 += xs[1][c] * wv;
    }
    float* vp = vbuf + ((size_t)(b * NH + h) * TDIM + j0) * DHS + d;
    vp[0 * DHS] = a0; vp[1 * DHS] = a1;
}

// wei: i-tile 4, 4-way c-split, 1024 threads, 2 blocks/CU.
__global__ __launch_bounds__(1024, 8) void k_wei(
    const float* __restrict__ PT, const float* __restrict__ Qb,
    const float* __restrict__ RT, const float* __restrict__ att_w2,
    const float* __restrict__ att_b2, int l, float* __restrict__ wei) {
    int bid = blockIdx.x;          // 512
    int bh = bid & 7;
    int b = bh >> 2, h = bh & 3;
    int i0 = (63 - (bid >> 3)) * 4;   // biggest tiles first
    int t = threadIdx.x;           // 0..1023
    int j = t & 255;
    int cs = t >> 8;               // c-split 0..3
    __shared__ float shQ[4][256];
    __shared__ float shW[256];
    __shared__ float part[4][4][256];  // [cs][ii][j]
    shQ[cs][j] = Qb[((b * TDIM + (i0 + cs)) * NH + h) * CDIM + j];
    if (t < 256) shW[t] = att_w2[(l * NH + h) * CDIM + t];
    __syncthreads();
    float acc0 = 0, acc1 = 0, acc2 = 0, acc3 = 0;
    int m = i0 - j;
    if ((t & 192) <= i0 + 3) {     // wave-uniform skip of fully-masked j-ranges
        bool v0 = m >= 0, v1 = m >= -1, v2 = m >= -2, v3 = m >= -3;
        const float* pp = PT + ((size_t)(b * NH + h) * CDIM) * TDIM + j;
        const float* rr = RT + ((size_t)h * CDIM) * TDIM + m;
        int c0 = cs * 64;
        #pragma unroll 4
        for (int c = c0; c < c0 + 64; ++c) {
            float p = pp[(size_t)c * TDIM];
            float w2v = shW[c];
            float r0v = v0 ? rr[(size_t)c * TDIM + 0] : 0.f;
            float r1v = v1 ? rr[(size_t)c * TDIM + 1] : 0.f;
            float r2v = v2 ? rr[(size_t)c * TDIM + 2] : 0.f;
            float r3v = v3 ? rr[(size_t)c * TDIM + 3] : 0.f;
            acc0 = fmaf(gelu_fast(p + shQ[0][c] + r0v), w2v, acc0);
            acc1 = fmaf(gelu_fast(p + shQ[1][c] + r1v), w2v, acc1);
            acc2 = fmaf(gelu_fast(p + shQ[2][c] + r2v), w2v, acc2);
            acc3 = fmaf(gelu_fast(p + shQ[3][c] + r3v), w2v, acc3);
        }
    }
    part[cs][0][j] = acc0; part[cs][1][j] = acc1;
    part[cs][2][j] = acc2; part[cs][3][j] = acc3;
    __syncthreads();
    if (t < 256) {
        #pragma unroll
        for (int ii = 0; ii < 4; ++ii) {
            float s = part[0][ii][t] + part[1][ii][t] + part[2][ii][t] + part[3][ii][t];
            part[0][ii][t] = s;   // column t only: no cross-thread hazard
        }
    }
    __syncthreads();
    if (t < 256) {
        float b2 = att_b2[l * NH + h];
        int lane = t & 63, w = t >> 6;
        int i = i0 + w;
        float lv[4];
        #pragma unroll
        for (int s = 0; s < 4; ++s) {
            int jj = lane + s * 64;
            lv[s] = (jj <= i) ? (part[0][w][jj] + b2) * 0.0625f : -1e30f;
        }
        float mx = fmaxf(fmaxf(lv[0], lv[1]), fmaxf(lv[2], lv[3]));
        #pragma unroll
        for (int off = 32; off; off >>= 1) mx = fmaxf(mx, __shfl_xor(mx, off));
        float es[4], sum = 0.f;
        #pragma unroll
        for (int s = 0; s < 4; ++s) { es[s] = exp2f((lv[s] - mx) * 1.4426950409f); sum += es[s]; }
        #pragma unroll
        for (int off = 32; off; off >>= 1) sum += __shfl_xor(sum, off);
        float inv = 1.0f / sum;
        float* wrow = wei + ((size_t)(b * NH + h) * TDIM + i) * TDIM;
        #pragma unroll
        for (int s = 0; s < 4; ++s) wrow[lane + s * 64] = es[s] * inv;
    }
}

// attn[b,i,h*64+d] = sum_{j<=i} wei * v. 4 j-strip waves + LDS reduce.
__global__ void k_av(const float* __restrict__ wei, const float* __restrict__ vbuf,
                     float* __restrict__ attn) {
    int bid = blockIdx.x;
    int i = bid & 255;
    int h = (bid >> 8) & (NH - 1);
    int b = bid >> 10;
    int t = threadIdx.x;           // 256
    int s = t >> 6;                // j-strip
    int d = t & 63;
    __shared__ float part[4][DHS];
    const float* wrow = wei + ((size_t)(b * NH + h) * TDIM + i) * TDIM;
    const float* vp = vbuf + ((size_t)(b * NH + h) * TDIM) * DHS + d;
    float acc = 0.f;
    int jend = min(i + 1, (s + 1) * 64);
    for (int j = s * 64; j < jend; ++j) acc += wrow[j] * vp[(size_t)j * DHS];
    part[s][d] = acc;
    __syncthreads();
    if (t < DHS) {
        float r = part[0][t] + part[1][t] + part[2][t] + part[3][t];
        attn[(b * TDIM + i) * CDIM + h * DHS + t] = r;
    }
}

// fused: x += attn@proj_w + proj_b;  hbuf_bf = bf16(LN(x)). 2 rows/block.
__global__ void k_proj_ln(const float* __restrict__ attn, const float* __restrict__ proj_w,
                          const float* __restrict__ proj_b, int l, float* __restrict__ x,
                          const float* __restrict__ lg, const float* __restrict__ lb,
                          unsigned short* __restrict__ hbuf_bf) {
    int bi0 = blockIdx.x * 2;
    int t = threadIdx.x;           // 256
    __shared__ float as[2][CDIM];
    __shared__ float rA[CDIM], rB[CDIM];
    for (int q = t; q < 2 * CDIM; q += 256) as[q >> 8][q & 255] = attn[bi0 * CDIM + q];
    __syncthreads();
    const float* w = proj_w + (size_t)l * CDIM * CDIM + t;
    float bb = proj_b[l * CDIM + t];
    float a0 = bb, a1 = bb;
    for (int z = 0; z < CDIM; ++z) {
        float wv = w[(size_t)z * CDIM];
        a0 += as[0][z] * wv; a1 += as[1][z] * wv;
    }
    float xn0 = x[(bi0 + 0) * CDIM + t] + a0;
    float xn1 = x[(bi0 + 1) * CDIM + t] + a1;
    x[(bi0 + 0) * CDIM + t] = xn0;
    x[(bi0 + 1) * CDIM + t] = xn1;
    rA[t] = xn0; rB[t] = xn1; __syncthreads();
    for (int s = 128; s > 0; s >>= 1) { if (t < s) { rA[t] += rA[t + s]; rB[t] += rB[t + s]; } __syncthreads(); }
    float mu0 = rA[0] * (1.f / 256.f), mu1 = rB[0] * (1.f / 256.f); __syncthreads();
    float d0 = xn0 - mu0, d1 = xn1 - mu1;
    rA[t] = d0 * d0; rB[t] = d1 * d1; __syncthreads();
    for (int s = 128; s > 0; s >>= 1) { if (t < s) { rA[t] += rA[t + s]; rB[t] += rB[t + s]; } __syncthreads(); }
    float r0 = rsqrtf(rA[0] * (1.f / 256.f) + 1e-5f);
    float r1 = rsqrtf(rB[0] * (1.f / 256.f) + 1e-5f);
    float gg = lg[t], bl = lb[t];
    hbuf_bf[(bi0 + 0) * CDIM + t] = f2bf(d0 * r0 * gg + bl);
    hbuf_bf[(bi0 + 1) * CDIM + t] = f2bf(d1 * r1 * gg + bl);
}

// final LN -> bf16
__global__ void k_lnf_bf16(const float* __restrict__ x, const float* __restrict__ g,
                           const float* __restrict__ bb, unsigned short* __restrict__ out) {
    int bi = blockIdx.x;
    int t = threadIdx.x;           // 256
    __shared__ float red[CDIM];
    float val = x[bi * CDIM + t];
    red[t] = val; __syncthreads();
    for (int s = 128; s > 0; s >>= 1) { if (t < s) red[t] += red[t + s]; __syncthreads(); }
    float mean = red[0] * (1.f / 256.f); __syncthreads();
    float dv = val - mean;
    red[t] = dv * dv; __syncthreads();
    for (int s = 128; s > 0; s >>= 1) { if (t < s) red[t] += red[t + s]; __syncthreads(); }
    float r = rsqrtf(red[0] * (1.f / 256.f) + 1e-5f);
    out[bi * CDIM + t] = f2bf(dv * r * g[t] + bb[t]);
}

extern "C" void kernel_launch(void* const* d_in, const int* in_sizes, int n_in,
                              void* d_out, int out_size, void* d_ws, size_t ws_size,
                              hipStream_t stream) {
    const int*   idx       = (const int*)  d_in[0];
    const float* tok_emb   = (const float*)d_in[1];
    const float* pos_table = (const float*)d_in[2];
    const float* pos_w1    = (const float*)d_in[3];
    const float* pos_w2    = (const float*)d_in[4];
    const float* pos_b2    = (const float*)d_in[5];
    const float* pos_ln_g  = (const float*)d_in[6];
    const float* pos_ln_b  = (const float*)d_in[7];
    const float* att_w1    = (const float*)d_in[8];
    const float* att_w2    = (const float*)d_in[9];
    const float* att_b2    = (const float*)d_in[10];
    const float* val_w     = (const float*)d_in[11];
    const float* proj_w    = (const float*)d_in[12];
    const float* proj_b    = (const float*)d_in[13];
    const float* ln2_g     = (const float*)d_in[14];
    const float* ln2_b     = (const float*)d_in[15];
    const float* ff_w1     = (const float*)d_in[16];
    const float* ff_w2     = (const float*)d_in[17];
    const float* ff_b2     = (const float*)d_in[18];
    const float* lnf_g     = (const float*)d_in[19];
    const float* lnf_b     = (const float*)d_in[20];
    const float* head_w    = (const float*)d_in[21];
    const float* head_b    = (const float*)d_in[22];
    float* out = (float*)d_out;

    float* ws = (float*)d_ws;
    float* x    = ws;  ws += NB * TDIM * CDIM;        // 131072
    float* PT   = ws;  ws += NB * NH * CDIM * TDIM;   // 524288
    float* Qb   = ws;  ws += NB * TDIM * NH * CDIM;   // 524288
    float* RT   = ws;  ws += NH * CDIM * TDIM;        // 262144
    float* vbuf = ws;  ws += NB * NH * TDIM * DHS;    // 131072
    float* wei  = ws;  ws += NB * NH * TDIM * TDIM;   // 524288 (2MB)
    float* attn = ws;  ws += NB * TDIM * CDIM;        // 131072
    unsigned short* x_bf    = (unsigned short*)ws; ws += NB * TDIM * CDIM / 2;
    unsigned short* ped_bf  = (unsigned short*)ws; ws += TDIM * 2 * CDIM / 2;
    unsigned short* hbuf_bf = (unsigned short*)ws; ws += NB * TDIM * CDIM / 2;
    unsigned short* xf_bf   = (unsigned short*)ws; ws += NB * TDIM * CDIM / 2;
    unsigned short* wT      = (unsigned short*)ws; ws += NV * CDIM / 2;
    unsigned short* W1r     = (unsigned short*)ws; ws += 2 * 1024 * 512 / 2;
    unsigned short* Wff1    = (unsigned short*)ws; ws += 2 * 1024 * 256 / 2;
    unsigned short* Wff2    = (unsigned short*)ws; ws += 2 * 256 * 1024 / 2;
    // fbuf_bf aliases wei: lifetimes disjoint (wei: k_wei->k_av; fbuf: k_ff1->k_ff2)
    unsigned short* fbuf_bf = (unsigned short*)wei;
    // total ~18.3 MB

    // weight transpose+casts (independent)
    k_tcast<<<dim3(NV / 32, CDIM / 32, 1), 256, 0, stream>>>(head_w, wT, 256, NV);
    k_tcast<<<dim3(256 / 32, 512 / 32, 8), 256, 0, stream>>>(att_w1, W1r, 512, 256);
    k_tcast<<<dim3(FHID / 32, 256 / 32, 2), 256, 0, stream>>>(ff_w1, Wff1, 256, FHID);
    k_tcast<<<dim3(256 / 32, FHID / 32, 2), 256, 0, stream>>>(ff_w2, Wff2, FHID, 256);

    k_embed<<<NB * TDIM, CDIM, 0, stream>>>(idx, tok_emb, x, x_bf);
    k_pe<<<TDIM, 512, 0, stream>>>(pos_table, pos_w1, pos_w2, pos_b2, pos_ln_g, pos_ln_b, ped_bf);

    for (int l = 0; l < 2; ++l) {
        k_pq_gemm<<<dim3(8, 32), 256, 0, stream>>>(x_bf, W1r, PT, Qb, l);
        k_r_gemm<<<dim3(4, 16), 256, 0, stream>>>(ped_bf, W1r, RT, l);
        k_v<<<NB * TDIM / 2, 256, 0, stream>>>(x, val_w, l, vbuf);
        k_wei<<<NB * NH * TDIM / 4, 1024, 0, stream>>>(PT, Qb, RT, att_w2, att_b2, l, wei);
        k_av<<<NB * NH * TDIM, 256, 0, stream>>>(wei, vbuf, attn);
        k_proj_ln<<<NB * TDIM / 2, 256, 0, stream>>>(attn, proj_w, proj_b, l, x,
                                                     ln2_g + l * CDIM, ln2_b + l * CDIM, hbuf_bf);
        k_ff1_gemm<<<dim3(8, 16), 256, 0, stream>>>(hbuf_bf, Wff1, fbuf_bf, l);
        k_ff2_gemm<<<dim3(8, 4), 256, 0, stream>>>(fbuf_bf, Wff2, ff_b2, x, x_bf, l);
    }

    k_lnf_bf16<<<NB * TDIM, 256, 0, stream>>>(x, lnf_g, lnf_b, xf_bf);
    k_head_mfma<<<dim3(8, 125), 256, 0, stream>>>(xf_bf, wT, head_b, out);
}

// Round 5
// 344.151 us; speedup vs baseline: 2.7509x; 1.2274x over previous
//
#include <hip/hip_runtime.h>
#include <hip/hip_bf16.h>
#include <math.h>

// Problem dims (fixed)
constexpr int TDIM = 256;   // sequence length t
constexpr int CDIM = 256;   // channels C
constexpr int NH   = 4;     // heads
constexpr int DHS  = 64;    // head size
constexpr int FHID = 1024;  // ffn hidden
constexpr int NV   = 8000;  // vocab
constexpr int NB   = 2;     // batch

typedef __attribute__((ext_vector_type(8))) short bf16x8;
typedef __attribute__((ext_vector_type(4))) float f32x4;
typedef __attribute__((ext_vector_type(2))) float f32x2;
typedef __attribute__((ext_vector_type(4))) unsigned int uint4v;

__device__ __forceinline__ float gelu_f(float x) {
    return 0.5f * x * (1.0f + erff(x * 0.70710678118654752440f));
}

// packed tanh-form gelu on 2 lanes: x*E/(E+1), E=exp2(x*(kA+kB*x^2))
__device__ __forceinline__ f32x2 gelu2(f32x2 x) {
    constexpr float kA = 2.0f * 1.4426950408889634f * 0.7978845608028654f;
    constexpr float kB = kA * 0.044715f;
    f32x2 arg = x * (kA + kB * (x * x));
    arg.x = fminf(arg.x, 120.f);
    arg.y = fminf(arg.y, 120.f);
    float e0 = exp2f(arg.x), e1 = exp2f(arg.y);
    f32x2 num; num.x = x.x * e0; num.y = x.y * e1;
    f32x2 den; den.x = __builtin_amdgcn_rcpf(e0 + 1.f); den.y = __builtin_amdgcn_rcpf(e1 + 1.f);
    return num * den;
}

__device__ __forceinline__ unsigned short f2bf(float f) {
    unsigned int u = __float_as_uint(f);
    unsigned int r = (u + 0x7FFF + ((u >> 16) & 1)) >> 16;   // RNE
    return (unsigned short)r;
}

// ---------------- merged weight transpose+cast (all 6 tensors, one launch) ----------
__global__ __launch_bounds__(256) void k_tcast_all(
    const float* __restrict__ head_w, const float* __restrict__ att_w1,
    const float* __restrict__ ff_w1, const float* __restrict__ ff_w2,
    const float* __restrict__ val_w, const float* __restrict__ proj_w,
    unsigned short* __restrict__ wT, unsigned short* __restrict__ W1r,
    unsigned short* __restrict__ Wff1, unsigned short* __restrict__ Wff2,
    unsigned short* __restrict__ Wv, unsigned short* __restrict__ Wproj)
{
    int q = blockIdx.x;
    const float* src; unsigned short* dst; int R, C, tx, ty;
    if (q < 2000)      { src = head_w; dst = wT; R = 256; C = 8000; tx = q % 250; ty = q / 250; }
    else if (q < 3024) { int u = q - 2000, s = u >> 7, v = u & 127;
        src = att_w1 + (size_t)s * 512 * 256; dst = W1r + (size_t)s * 512 * 256;
        R = 512; C = 256; tx = v & 7; ty = v >> 3; }
    else if (q < 3536) { int u = q - 3024, s = u >> 8, v = u & 255;
        src = ff_w1 + (size_t)s * 256 * 1024; dst = Wff1 + (size_t)s * 256 * 1024;
        R = 256; C = 1024; tx = v & 31; ty = v >> 5; }
    else if (q < 4048) { int u = q - 3536, s = u >> 8, v = u & 255;
        src = ff_w2 + (size_t)s * 1024 * 256; dst = Wff2 + (size_t)s * 1024 * 256;
        R = 1024; C = 256; tx = v & 7; ty = v >> 3; }
    else if (q < 4176) { int u = q - 4048, s = u >> 4, v = u & 15;
        src = val_w + (size_t)s * 256 * 64; dst = Wv + (size_t)s * 256 * 64;
        R = 256; C = 64; tx = v & 1; ty = v >> 1; }
    else { int u = q - 4176, s = u >> 6, v = u & 63;
        src = proj_w + (size_t)s * 256 * 256; dst = Wproj + (size_t)s * 256 * 256;
        R = 256; C = 256; tx = v & 7; ty = v >> 3; }
    __shared__ float tile[32][33];
    int c0 = tx * 32, r0 = ty * 32, t = threadIdx.x;
    #pragma unroll
    for (int e = 0; e < 4; ++e) {
        int lin = e * 256 + t; int rr = lin >> 5, cc = lin & 31;
        tile[rr][cc] = src[(size_t)(r0 + rr) * C + c0 + cc];
    }
    __syncthreads();
    #pragma unroll
    for (int e = 0; e < 4; ++e) {
        int lin = e * 256 + t; int cc = lin >> 5, rr = lin & 31;
        dst[(size_t)(c0 + cc) * R + r0 + rr] = f2bf(tile[rr][cc]);
    }
}

// x[b,t,:] = tok_emb[idx[b,t]] (f32 + bf16 copies)
__global__ void k_embed(const int* __restrict__ idx, const float* __restrict__ tok_emb,
                        float* __restrict__ x, unsigned short* __restrict__ x_bf) {
    int bt = blockIdx.x;           // 0..511
    int c  = threadIdx.x;          // 256
    int tok = idx[bt];
    float v = tok_emb[(size_t)tok * CDIM + c];
    x[bt * CDIM + c] = v;
    x_bf[bt * CDIM + c] = f2bf(v);
}

// fused pe: ped_bf[d,:512] = bf16(LN(gelu(pos_table[d]@pos_w1) @ pos_w2 + pos_b2))
__global__ void k_pe(const float* __restrict__ pos_table, const float* __restrict__ pos_w1,
                     const float* __restrict__ pos_w2, const float* __restrict__ pos_b2,
                     const float* __restrict__ g, const float* __restrict__ bb,
                     unsigned short* __restrict__ ped_bf) {
    int d = blockIdx.x;
    int t = threadIdx.x;           // 512
    __shared__ float xs[CDIM];
    __shared__ float hs[512];
    __shared__ float red[512];
    if (t < CDIM) xs[t] = pos_table[d * CDIM + t];
    __syncthreads();
    float acc = 0.f;
    for (int c = 0; c < CDIM; ++c) acc += xs[c] * pos_w1[(size_t)c * 512 + t];
    hs[t] = gelu_f(acc);
    __syncthreads();
    float acc2 = pos_b2[t];
    for (int z = 0; z < 512; ++z) acc2 += hs[z] * pos_w2[(size_t)z * 512 + t];
    red[t] = acc2; __syncthreads();
    for (int s = 256; s > 0; s >>= 1) { if (t < s) red[t] += red[t + s]; __syncthreads(); }
    float mean = red[0] * (1.f / 512.f); __syncthreads();
    float dv = acc2 - mean;
    red[t] = dv * dv; __syncthreads();
    for (int s = 256; s > 0; s >>= 1) { if (t < s) red[t] += red[t + s]; __syncthreads(); }
    float r = rsqrtf(red[0] * (1.f / 512.f) + 1e-5f);
    ped_bf[d * 512 + t] = f2bf(dv * r * g[t] + bb[t]);
}

// ---------------- shared bf16 MFMA 64x64-tile core (proven in R2/R3) ----------------
__device__ __forceinline__ void gemm64_core(
    const unsigned short* __restrict__ A, int lda,
    const unsigned short* __restrict__ B, int ldb,
    int kLen, int t, f32x4 acc[2][2],
    unsigned short* __restrict__ A_lds, unsigned short* __restrict__ B_lds)
{
    int lane = t & 63;
    int w = t >> 6;
    int wm = (w >> 1) * 32, wn = (w & 1) * 32;
    int l15 = lane & 15;
    int lk = (lane >> 4) * 8;
    for (int kc = 0; kc < kLen; kc += 256) {
        #pragma unroll
        for (int it = 0; it < 8; ++it) {
            int chunk = it * 256 + t;       // 2048 x 16B chunks
            int row = chunk >> 5;           // 32 chunks per 256-col row
            int c16 = chunk & 31;
            uint4v va = *(const uint4v*)(A + (size_t)row * lda + kc + c16 * 8);
            uint4v vb = *(const uint4v*)(B + (size_t)row * ldb + kc + c16 * 8);
            int lin = row * 512 + c16 * 16;
            int phys = lin ^ ((row & 7) << 4);
            *(uint4v*)((char*)A_lds + phys) = va;
            *(uint4v*)((char*)B_lds + phys) = vb;
        }
        __syncthreads();
        #pragma unroll
        for (int ks = 0; ks < 8; ++ks) {
            int kb = ks * 32 + lk;
            bf16x8 a[2], b[2];
            #pragma unroll
            for (int f = 0; f < 2; ++f) {
                int mrow = wm + f * 16 + l15;
                int lina = mrow * 512 + kb * 2;
                a[f] = *(const bf16x8*)((const char*)A_lds + (lina ^ ((mrow & 7) << 4)));
                int nrow = wn + f * 16 + l15;
                int linb = nrow * 512 + kb * 2;
                b[f] = *(const bf16x8*)((const char*)B_lds + (linb ^ ((nrow & 7) << 4)));
            }
            acc[0][0] = __builtin_amdgcn_mfma_f32_16x16x32_bf16(a[0], b[0], acc[0][0], 0, 0, 0);
            acc[0][1] = __builtin_amdgcn_mfma_f32_16x16x32_bf16(a[0], b[1], acc[0][1], 0, 0, 0);
            acc[1][0] = __builtin_amdgcn_mfma_f32_16x16x32_bf16(a[1], b[0], acc[1][0], 0, 0, 0);
            acc[1][1] = __builtin_amdgcn_mfma_f32_16x16x32_bf16(a[1], b[1], acc[1][1], 0, 0, 0);
        }
        __syncthreads();
    }
}

// merged QKV: bid<256 -> pq GEMM; 256..319 -> r GEMM; 320..351 -> v GEMM
__global__ __launch_bounds__(256) void k_qkv(
    const unsigned short* __restrict__ x_bf,   // [512][256]
    const unsigned short* __restrict__ ped_bf, // [256][512]
    const unsigned short* __restrict__ W1r,    // [L*4][256][512]
    const unsigned short* __restrict__ Wv,     // [L*4][64][256]
    float* __restrict__ PT, float* __restrict__ Qb, float* __restrict__ RT,
    unsigned short* __restrict__ vT_bf, int l)
{
    __shared__ unsigned short A_lds[64 * 256];
    __shared__ unsigned short B_lds[64 * 256];
    int t = threadIdx.x;
    int bid = blockIdx.x;
    int lane = t & 63, w = t >> 6;
    int wm = (w >> 1) * 32, wn = (w & 1) * 32;
    int l15 = lane & 15;
    f32x4 acc[2][2] = {};
    if (bid < 256) {           // pq: out[512,2048] = x_bf @ W1
        int r0 = (bid & 7) * 64;
        int n0 = (bid >> 3) * 64;
        int h = n0 >> 9, isQ = (n0 >> 8) & 1;
        const unsigned short* Bp = W1r + (size_t)l * 1024 * 512
                                 + (size_t)(h * 256 + (n0 & 255)) * 512 + isQ * 256;
        gemm64_core(x_bf + (size_t)r0 * 256, 256, Bp, 512, 256, t, acc, A_lds, B_lds);
        #pragma unroll
        for (int fm = 0; fm < 2; ++fm)
        #pragma unroll
        for (int fn = 0; fn < 2; ++fn) {
            int col = n0 + wn + fn * 16 + l15;
            int c = col & 255;
            #pragma unroll
            for (int r = 0; r < 4; ++r) {
                int row = r0 + wm + fm * 16 + (lane >> 4) * 4 + r;
                int b = row >> 8, ij = row & 255;
                if (isQ) Qb[((b * TDIM + ij) * NH + h) * CDIM + c] = acc[fm][fn][r];
                else     PT[((size_t)(b * NH + h) * CDIM + c) * TDIM + ij] = acc[fm][fn][r];
            }
        }
    } else if (bid < 320) {    // r: out[256 d, 1024 (h,c)] = ped_bf @ W1r^T
        int u = bid - 256;
        int r0 = (u & 3) * 64;
        int n0 = (u >> 2) * 64;
        const unsigned short* Bp = W1r + (size_t)l * 1024 * 512 + (size_t)n0 * 512;
        gemm64_core(ped_bf + (size_t)r0 * 512, 512, Bp, 512, 512, t, acc, A_lds, B_lds);
        #pragma unroll
        for (int fm = 0; fm < 2; ++fm)
        #pragma unroll
        for (int fn = 0; fn < 2; ++fn) {
            int col = n0 + wn + fn * 16 + l15;
            #pragma unroll
            for (int r = 0; r < 4; ++r) {
                int d = r0 + wm + fm * 16 + (lane >> 4) * 4 + r;
                RT[(size_t)col * TDIM + d] = acc[fm][fn][r];
            }
        }
    } else {                   // v: out[512 (b,j), 256 (h,d)] = x_bf @ Wv^T -> vT_bf[(b,h,d)][j]
        int u = bid - 320;
        int r0 = (u & 7) * 64;
        int n0 = (u >> 3) * 64;
        int h = n0 >> 6;
        const unsigned short* Bp = Wv + ((size_t)l * NH + h) * DHS * CDIM;
        gemm64_core(x_bf + (size_t)r0 * 256, 256, Bp, 256, 256, t, acc, A_lds, B_lds);
        #pragma unroll
        for (int fm = 0; fm < 2; ++fm)
        #pragma unroll
        for (int fn = 0; fn < 2; ++fn) {
            int col = n0 + wn + fn * 16 + l15;
            int d = col & 63;
            #pragma unroll
            for (int r = 0; r < 4; ++r) {
                int row = r0 + wm + fm * 16 + (lane >> 4) * 4 + r;
                int b = row >> 8, j = row & 255;
                vT_bf[(((size_t)b * NH + h) * DHS + d) * TDIM + j] = f2bf(acc[fm][fn][r]);
            }
        }
    }
}

// wei: i-tile 4, 4-way c-split, 1024 threads. Packed math + b128 loads, no predicates.
__global__ __launch_bounds__(1024, 8) void k_wei(
    const float* __restrict__ PT, const float* __restrict__ Qb,
    const float* __restrict__ RT, const float* __restrict__ att_w2,
    const float* __restrict__ att_b2, int l, unsigned short* __restrict__ wei_bf) {
    int bid = blockIdx.x;          // 512
    int bh = bid & 7;
    int b = bh >> 2, h = bh & 3;
    int i0 = (63 - (bid >> 3)) * 4;   // biggest tiles first
    int t = threadIdx.x;           // 0..1023
    int j = t & 255;
    int cs = t >> 8;               // c-split 0..3
    __shared__ float shQW[256][8];     // [c][q0..q3, w2, pad]
    __shared__ float part[4][4][256];  // [cs][ii][j]
    { int ii = t >> 8, c = t & 255;
      shQW[c][ii] = Qb[((b * TDIM + (i0 + ii)) * NH + h) * CDIM + c]; }
    if (t < 256) shQW[t][4] = att_w2[(l * NH + h) * CDIM + t];
    __syncthreads();
    f32x2 accA = {0.f, 0.f}, accB = {0.f, 0.f};
    int m = i0 - j;
    int mm = max(m, -3);           // clamped base; garbage lanes are the discarded j>i lanes
    if ((t & 192) <= i0 + 3) {     // wave-uniform skip of fully-masked j-strips
        const float* pp = PT + ((size_t)(b * NH + h) * CDIM) * TDIM + j;
        const float* rr = RT + ((size_t)h * CDIM) * TDIM + mm;
        int c0 = cs * 64;
        #pragma unroll 4
        for (int c = c0; c < c0 + 64; ++c) {
            float p = pp[(size_t)c * TDIM];
            f32x4 r4; __builtin_memcpy(&r4, rr + (size_t)c * TDIM, 16);
            f32x4 q4 = *(const f32x4*)(&shQW[c][0]);
            float w2v = shQW[c][4];
            f32x2 zA, zB;
            zA.x = p + q4.x + r4.x; zA.y = p + q4.y + r4.y;
            zB.x = p + q4.z + r4.z; zB.y = p + q4.w + r4.w;
            accA += gelu2(zA) * w2v;
            accB += gelu2(zB) * w2v;
        }
    }
    part[cs][0][j] = accA.x; part[cs][1][j] = accA.y;
    part[cs][2][j] = accB.x; part[cs][3][j] = accB.y;
    __syncthreads();
    if (t < 256) {
        #pragma unroll
        for (int ii = 0; ii < 4; ++ii) {
            float s = part[0][ii][t] + part[1][ii][t] + part[2][ii][t] + part[3][ii][t];
            part[0][ii][t] = s;
        }
    }
    __syncthreads();
    if (t < 256) {
        float b2 = att_b2[l * NH + h];
        int lane = t & 63, w = t >> 6;
        int i = i0 + w;
        float lv[4];
        #pragma unroll
        for (int s = 0; s < 4; ++s) {
            int jj = lane + s * 64;
            lv[s] = (jj <= i) ? (part[0][w][jj] + b2) * 0.0625f : -1e30f;
        }
        float mx = fmaxf(fmaxf(lv[0], lv[1]), fmaxf(lv[2], lv[3]));
        #pragma unroll
        for (int off = 32; off; off >>= 1) mx = fmaxf(mx, __shfl_xor(mx, off));
        float es[4], sum = 0.f;
        #pragma unroll
        for (int s = 0; s < 4; ++s) { es[s] = exp2f((lv[s] - mx) * 1.4426950409f); sum += es[s]; }
        #pragma unroll
        for (int off = 32; off; off >>= 1) sum += __shfl_xor(sum, off);
        float inv = 1.0f / sum;
        unsigned short* wrow = wei_bf + (((size_t)bh * TDIM) + i) * TDIM;
        #pragma unroll
        for (int s = 0; s < 4; ++s) wrow[lane + s * 64] = f2bf(es[s] * inv);
    }
}

// av GEMM: attn_bf[(b,i)][(h,d)] = wei_bf[(b,h)] @ vT_bf[(b,h)]^T. grid 32.
__global__ __launch_bounds__(256) void k_av_gemm(
    const unsigned short* __restrict__ wei_bf,  // [8][256][256]
    const unsigned short* __restrict__ vT_bf,   // [8][64][256]
    unsigned short* __restrict__ attn_bf)       // [512][256]
{
    __shared__ unsigned short A_lds[64 * 256];
    __shared__ unsigned short B_lds[64 * 256];
    int t = threadIdx.x;
    int bid = blockIdx.x;          // 32: bh = bid>>2, m-tile = bid&3
    int bh = bid >> 2;
    int r0 = (bid & 3) * 64;
    int b = bh >> 2, h = bh & 3;
    f32x4 acc[2][2] = {};
    gemm64_core(wei_bf + (size_t)bh * 65536 + (size_t)r0 * 256, 256,
                vT_bf + (size_t)bh * 16384, 256, 256, t, acc, A_lds, B_lds);
    int lane = t & 63, w = t >> 6;
    int wm = (w >> 1) * 32, wn = (w & 1) * 32;
    int l15 = lane & 15;
    #pragma unroll
    for (int fm = 0; fm < 2; ++fm)
    #pragma unroll
    for (int fn = 0; fn < 2; ++fn) {
        int d = wn + fn * 16 + l15;    // 0..63
        #pragma unroll
        for (int r = 0; r < 4; ++r) {
            int i = r0 + wm + fm * 16 + (lane >> 4) * 4 + r;
            attn_bf[((size_t)(b * TDIM + i)) * CDIM + h * DHS + d] = f2bf(acc[fm][fn][r]);
        }
    }
}

// proj GEMM: pbuf[512,256] = attn_bf @ Wproj^T + proj_b. grid (8,4)=32.
__global__ __launch_bounds__(256) void k_proj_gemm(
    const unsigned short* __restrict__ attn_bf, // [512][256]
    const unsigned short* __restrict__ Wproj,   // [L][256][256]
    const float* __restrict__ proj_b,
    float* __restrict__ pbuf, int l)
{
    __shared__ unsigned short A_lds[64 * 256];
    __shared__ unsigned short B_lds[64 * 256];
    int t = threadIdx.x;
    int r0 = (blockIdx.x & 7) * 64;
    int n0 = (blockIdx.x >> 3) * 64;
    f32x4 acc[2][2] = {};
    gemm64_core(attn_bf + (size_t)r0 * 256, 256,
                Wproj + (size_t)l * 65536 + (size_t)n0 * 256, 256, 256, t, acc, A_lds, B_lds);
    int lane = t & 63, w = t >> 6;
    int wm = (w >> 1) * 32, wn = (w & 1) * 32;
    int l15 = lane & 15;
    #pragma unroll
    for (int fm = 0; fm < 2; ++fm)
    #pragma unroll
    for (int fn = 0; fn < 2; ++fn) {
        int col = n0 + wn + fn * 16 + l15;
        float bb = proj_b[l * CDIM + col];
        #pragma unroll
        for (int r = 0; r < 4; ++r) {
            int row = r0 + wm + fm * 16 + (lane >> 4) * 4 + r;
            pbuf[(size_t)row * CDIM + col] = acc[fm][fn][r] + bb;
        }
    }
}

// fused residual + LN: x += pbuf; hbuf_bf = bf16(LN(x)). 512 blocks.
__global__ void k_resln(const float* __restrict__ pbuf, float* __restrict__ x,
                        const float* __restrict__ lg, const float* __restrict__ lb,
                        unsigned short* __restrict__ hbuf_bf) {
    int bi = blockIdx.x;
    int t = threadIdx.x;           // 256
    __shared__ float red[CDIM];
    float val = x[bi * CDIM + t] + pbuf[bi * CDIM + t];
    x[bi * CDIM + t] = val;
    red[t] = val; __syncthreads();
    for (int s = 128; s > 0; s >>= 1) { if (t < s) red[t] += red[t + s]; __syncthreads(); }
    float mean = red[0] * (1.f / 256.f); __syncthreads();
    float dv = val - mean;
    red[t] = dv * dv; __syncthreads();
    for (int s = 128; s > 0; s >>= 1) { if (t < s) red[t] += red[t + s]; __syncthreads(); }
    float r = rsqrtf(red[0] * (1.f / 256.f) + 1e-5f);
    hbuf_bf[bi * CDIM + t] = f2bf(dv * r * lg[t] + lb[t]);
}

// ff1 GEMM: fbuf_bf[512,1024] = bf16(gelu(hbuf_bf @ Wff1^T)). grid (8, 16).
__global__ __launch_bounds__(256) void k_ff1_gemm(
    const unsigned short* __restrict__ hbuf_bf, // [512][256]
    const unsigned short* __restrict__ Wff1,    // [L][1024][256]
    unsigned short* __restrict__ fbuf_bf, int l)
{
    __shared__ unsigned short A_lds[64 * 256];
    __shared__ unsigned short B_lds[64 * 256];
    int t = threadIdx.x;
    int r0 = blockIdx.x * 64;
    int n0 = blockIdx.y * 64;
    const unsigned short* Bp = Wff1 + (size_t)l * 1024 * 256 + (size_t)n0 * 256;
    f32x4 acc[2][2] = {};
    gemm64_core(hbuf_bf + (size_t)r0 * 256, 256, Bp, 256, 256, t, acc, A_lds, B_lds);
    int lane = t & 63, w = t >> 6;
    int wm = (w >> 1) * 32, wn = (w & 1) * 32;
    int l15 = lane & 15;
    #pragma unroll
    for (int fm = 0; fm < 2; ++fm)
    #pragma unroll
    for (int fn = 0; fn < 2; ++fn) {
        int col = n0 + wn + fn * 16 + l15;
        #pragma unroll
        for (int r = 0; r < 4; ++r) {
            int row = r0 + wm + fm * 16 + (lane >> 4) * 4 + r;
            fbuf_bf[(size_t)row * FHID + col] = f2bf(gelu_f(acc[fm][fn][r]));
        }
    }
}

// ff2 GEMM: x += fbuf_bf @ Wff2^T + b2; writes x f32 + x_bf. grid (8, 4). K=1024.
__global__ __launch_bounds__(256) void k_ff2_gemm(
    const unsigned short* __restrict__ fbuf_bf, // [512][1024]
    const unsigned short* __restrict__ Wff2,    // [L][256][1024]
    const float* __restrict__ ff_b2,
    float* __restrict__ x, unsigned short* __restrict__ x_bf, int l)
{
    __shared__ unsigned short A_lds[64 * 256];
    __shared__ unsigned short B_lds[64 * 256];
    int t = threadIdx.x;
    int r0 = blockIdx.x * 64;
    int n0 = blockIdx.y * 64;
    const unsigned short* Bp = Wff2 + (size_t)l * 256 * 1024 + (size_t)n0 * 1024;
    f32x4 acc[2][2] = {};
    gemm64_core(fbuf_bf + (size_t)r0 * 1024, 1024, Bp, 1024, 1024, t, acc, A_lds, B_lds);
    int lane = t & 63, w = t >> 6;
    int wm = (w >> 1) * 32, wn = (w & 1) * 32;
    int l15 = lane & 15;
    #pragma unroll
    for (int fm = 0; fm < 2; ++fm)
    #pragma unroll
    for (int fn = 0; fn < 2; ++fn) {
        int col = n0 + wn + fn * 16 + l15;
        float bb = ff_b2[l * CDIM + col];
        #pragma unroll
        for (int r = 0; r < 4; ++r) {
            int row = r0 + wm + fm * 16 + (lane >> 4) * 4 + r;
            float v = x[(size_t)row * CDIM + col] + acc[fm][fn][r] + bb;
            x[(size_t)row * CDIM + col] = v;
            x_bf[(size_t)row * CDIM + col] = f2bf(v);
        }
    }
}

// final LN -> bf16
__global__ void k_lnf_bf16(const float* __restrict__ x, const float* __restrict__ g,
                           const float* __restrict__ bb, unsigned short* __restrict__ out) {
    int bi = blockIdx.x;
    int t = threadIdx.x;           // 256
    __shared__ float red[CDIM];
    float val = x[bi * CDIM + t];
    red[t] = val; __syncthreads();
    for (int s = 128; s > 0; s >>= 1) { if (t < s) red[t] += red[t + s]; __syncthreads(); }
    float mean = red[0] * (1.f / 256.f); __syncthreads();
    float dv = val - mean;
    red[t] = dv * dv; __syncthreads();
    for (int s = 128; s > 0; s >>= 1) { if (t < s) red[t] += red[t + s]; __syncthreads(); }
    float r = rsqrtf(red[0] * (1.f / 256.f) + 1e-5f);
    out[bi * CDIM + t] = f2bf(dv * r * g[t] + bb[t]);
}

// head GEMM: out[512,8000] = xf_bf @ wT^T + head_b. grid (8, 125).
__global__ __launch_bounds__(256) void k_head_mfma(
    const unsigned short* __restrict__ xf_bf,   // [512][256]
    const unsigned short* __restrict__ wT,      // [8000][256]
    const float* __restrict__ head_b,
    float* __restrict__ out)
{
    __shared__ unsigned short A_lds[64 * 256];
    __shared__ unsigned short B_lds[64 * 256];
    int t = threadIdx.x;
    int r0 = blockIdx.x * 64;
    int n0 = blockIdx.y * 64;
    f32x4 acc[2][2] = {};
    gemm64_core(xf_bf + (size_t)r0 * 256, 256, wT + (size_t)n0 * 256, 256, 256,
                t, acc, A_lds, B_lds);
    int lane = t & 63, w = t >> 6;
    int wm = (w >> 1) * 32, wn = (w & 1) * 32;
    int l15 = lane & 15;
    #pragma unroll
    for (int fm = 0; fm < 2; ++fm)
    #pragma unroll
    for (int fn = 0; fn < 2; ++fn) {
        int col = n0 + wn + fn * 16 + l15;
        float hb = head_b[col];
        #pragma unroll
        for (int r = 0; r < 4; ++r) {
            int row = r0 + wm + fm * 16 + (lane >> 4) * 4 + r;
            out[(size_t)row * NV + col] = acc[fm][fn][r] + hb;
        }
    }
}

extern "C" void kernel_launch(void* const* d_in, const int* in_sizes, int n_in,
                              void* d_out, int out_size, void* d_ws, size_t ws_size,
                              hipStream_t stream) {
    const int*   idx       = (const int*)  d_in[0];
    const float* tok_emb   = (const float*)d_in[1];
    const float* pos_table = (const float*)d_in[2];
    const float* pos_w1    = (const float*)d_in[3];
    const float* pos_w2    = (const float*)d_in[4];
    const float* pos_b2    = (const float*)d_in[5];
    const float* pos_ln_g  = (const float*)d_in[6];
    const float* pos_ln_b  = (const float*)d_in[7];
    const float* att_w1    = (const float*)d_in[8];
    const float* att_w2    = (const float*)d_in[9];
    const float* att_b2    = (const float*)d_in[10];
    const float* val_w     = (const float*)d_in[11];
    const float* proj_w    = (const float*)d_in[12];
    const float* proj_b    = (const float*)d_in[13];
    const float* ln2_g     = (const float*)d_in[14];
    const float* ln2_b     = (const float*)d_in[15];
    const float* ff_w1     = (const float*)d_in[16];
    const float* ff_w2     = (const float*)d_in[17];
    const float* ff_b2     = (const float*)d_in[18];
    const float* lnf_g     = (const float*)d_in[19];
    const float* lnf_b     = (const float*)d_in[20];
    const float* head_w    = (const float*)d_in[21];
    const float* head_b    = (const float*)d_in[22];
    float* out = (float*)d_out;

    float* ws = (float*)d_ws;
    float* x    = ws;  ws += NB * TDIM * CDIM;        // 131072
    float* PT   = ws;  ws += NB * NH * CDIM * TDIM;   // 524288
    float* Qb   = ws;  ws += NB * TDIM * NH * CDIM;   // 524288
    ws += 16;                                         // guard before RT (k_wei reads RT-3)
    float* RT   = ws;  ws += NH * CDIM * TDIM;        // 262144
    float* pbuf = PT;                                 // alias: disjoint lifetimes
    unsigned short* x_bf    = (unsigned short*)ws; ws += NB * TDIM * CDIM / 2;
    unsigned short* ped_bf  = (unsigned short*)ws; ws += TDIM * 2 * CDIM / 2;
    unsigned short* hbuf_bf = (unsigned short*)ws; ws += NB * TDIM * CDIM / 2;
    unsigned short* xf_bf   = (unsigned short*)ws; ws += NB * TDIM * CDIM / 2;
    unsigned short* wei_bf  = (unsigned short*)ws; ws += NB * NH * TDIM * TDIM / 2;
    unsigned short* vT_bf   = (unsigned short*)ws; ws += NB * NH * DHS * TDIM / 2;
    unsigned short* attn_bf = (unsigned short*)ws; ws += NB * TDIM * CDIM / 2;
    unsigned short* wT      = (unsigned short*)ws; ws += NV * CDIM / 2;
    unsigned short* W1r     = (unsigned short*)ws; ws += 2 * 1024 * 512 / 2;
    unsigned short* Wff1    = (unsigned short*)ws; ws += 2 * 1024 * 256 / 2;
    unsigned short* Wff2    = (unsigned short*)ws; ws += 2 * 256 * 1024 / 2;
    unsigned short* Wv      = (unsigned short*)ws; ws += 2 * NH * DHS * CDIM / 2;
    unsigned short* Wproj   = (unsigned short*)ws; ws += 2 * CDIM * CDIM / 2;
    unsigned short* fbuf_bf = wei_bf;                 // alias: disjoint lifetimes
    // total ~17.2 MB

    k_tcast_all<<<4304, 256, 0, stream>>>(head_w, att_w1, ff_w1, ff_w2, val_w, proj_w,
                                          wT, W1r, Wff1, Wff2, Wv, Wproj);
    k_embed<<<NB * TDIM, CDIM, 0, stream>>>(idx, tok_emb, x, x_bf);
    k_pe<<<TDIM, 512, 0, stream>>>(pos_table, pos_w1, pos_w2, pos_b2, pos_ln_g, pos_ln_b, ped_bf);

    for (int l = 0; l < 2; ++l) {
        k_qkv<<<352, 256, 0, stream>>>(x_bf, ped_bf, W1r, Wv, PT, Qb, RT, vT_bf, l);
        k_wei<<<NB * NH * TDIM / 4, 1024, 0, stream>>>(PT, Qb, RT, att_w2, att_b2, l, wei_bf);
        k_av_gemm<<<32, 256, 0, stream>>>(wei_bf, vT_bf, attn_bf);
        k_proj_gemm<<<32, 256, 0, stream>>>(attn_bf, Wproj, proj_b, pbuf, l);
        k_resln<<<NB * TDIM, 256, 0, stream>>>(pbuf, x, ln2_g + l * CDIM, ln2_b + l * CDIM, hbuf_bf);
        k_ff1_gemm<<<dim3(8, 16), 256, 0, stream>>>(hbuf_bf, Wff1, fbuf_bf, l);
        k_ff2_gemm<<<dim3(8, 4), 256, 0, stream>>>(fbuf_bf, Wff2, ff_b2, x, x_bf, l);
    }

    k_lnf_bf16<<<NB * TDIM, 256, 0, stream>>>(x, lnf_g, lnf_b, xf_bf);
    k_head_mfma<<<dim3(8, 125), 256, 0, stream>>>(xf_bf, wT, head_b, out);
}